// Round 18
// baseline (250.912 us; speedup 1.0000x reference)
//
#include <hip/hip_runtime.h>
#include <hip/hip_bf16.h>
#include <cstddef>

typedef __attribute__((ext_vector_type(8))) short short8;
typedef __attribute__((ext_vector_type(4))) float f32x4;

#define NPIX 65536  // 256*256

static __device__ __forceinline__ unsigned short f2bs(float f) {
  __hip_bfloat16 h = __float2bfloat16(f);
  return __builtin_bit_cast(unsigned short, h);
}
static __device__ __forceinline__ float s2f(short s) {
  union { unsigned u; float f; } v; v.u = ((unsigned)(unsigned short)s) << 16;
  return v.f;
}

__global__ void k_zero(float* __restrict__ p, int n) {
  int i = blockIdx.x * 256 + threadIdx.x;
  if (i < n) p[i] = 0.f;
}

// ---- fused bank-1 pre-pass: mu1/rs1 per pixel, xg1 partial sums (no atomics), Gram M ----
__global__ __launch_bounds__(256, 4)
void k_statsxg(const float* __restrict__ in, float* __restrict__ mu,
               float* __restrict__ rs, const float* __restrict__ lnw,
               const float* __restrict__ lnb, float* __restrict__ part1,
               float* __restrict__ M) {
  __shared__ __align__(16) short tile[64 * 264];   // [c][256 px + pad]
  int t = threadIdx.x;
  int pi = blockIdx.x * 256 + t;
  int b = blockIdx.x >> 8;
  const float* p = in + ((size_t)b << 22) + (pi & 65535);
  float s = 0.f, s2 = 0.f;
  #pragma unroll
  for (int c = 0; c < 64; ++c) {
    float v = p[(size_t)c << 16];
    s += v; s2 += v * v;
    tile[c * 264 + t] = (short)f2bs(v);
  }
  float m = s * 0.015625f;
  float var = s2 * 0.015625f - m * m;
  float rstd = rsqrtf(var + 1e-5f);
  mu[pi] = m; rs[pi] = rstd;
  #pragma unroll
  for (int c = 0; c < 64; ++c) {
    float lnv = (s2f(tile[c * 264 + t]) - m) * rstd * lnw[c] + lnb[c];
    tile[c * 264 + t] = (short)f2bs(lnv);          // own column only
  }
  __syncthreads();
  // per-channel row sums -> 4-lane combine -> ONE plain store per (block, channel)
  {
    int cB = t >> 2, qB = t & 3;
    float rsum = 0.f;
    #pragma unroll
    for (int i = 0; i < 8; ++i) {
      short8 vv = *(const short8*)(tile + cB * 264 + (qB << 6) + (i << 3));
      #pragma unroll
      for (int j = 0; j < 8; ++j) rsum += s2f(vv[j]);
    }
    rsum += __shfl_xor(rsum, 1, 64);
    rsum += __shfl_xor(rsum, 2, 64);
    if (qB == 0) part1[blockIdx.x * 64 + cB] = rsum;
  }
  // Gram: wave w computes rows 16w..16w+15 x all 64 cols, K = 256 px
  int l = t & 63, w = t >> 6, l15 = l & 15, g = l >> 4;
  f32x4 ga[4] = {{0,0,0,0},{0,0,0,0},{0,0,0,0},{0,0,0,0}};
  #pragma unroll
  for (int kt = 0; kt < 8; ++kt) {
    short8 af = *(const short8*)(tile + (16 * w + l15) * 264 + (kt << 5) + (g << 3));
    #pragma unroll
    for (int ot = 0; ot < 4; ++ot) {
      short8 bfg = *(const short8*)(tile + ((ot << 4) + l15) * 264 + (kt << 5) + (g << 3));
      ga[ot] = __builtin_amdgcn_mfma_f32_16x16x32_bf16(af, bfg, ga[ot], 0, 0, 0);
    }
  }
  float* Mb = M + b * 4096;
  #pragma unroll
  for (int ot = 0; ot < 4; ++ot)
    #pragma unroll
    for (int r = 0; r < 4; ++r)
      atomicAdd(&Mb[(16 * w + (g << 2) + r) * 64 + (ot << 4) + l15], ga[ot][r]);
}

// ---------------- routing (256 thr): reduce 256 partials/(b,c), then route ----------------
__global__ __launch_bounds__(256)
void k_route(const float* __restrict__ part, const float* __restrict__ smr_part,
             const float* __restrict__ lnw, const float* __restrict__ lnb,
             const float* __restrict__ hid,
             const float* __restrict__ w1, const float* __restrict__ b1,
             const float* __restrict__ w3, const float* __restrict__ b3,
             float* __restrict__ h1_out, float* __restrict__ logit_out,
             float* __restrict__ out_logits, int slot,
             float* __restrict__ out_hidden) {
  __shared__ float xgs[4][64];
  __shared__ float smrs[4];
  __shared__ float h1s[4][16];
  int t = threadIdx.x;                             // 256 threads
  {
    int bb = t >> 6, c = t & 63;
    const float* pp = part + (bb << 14) + c;
    float s = 0.f;
    for (int k = 0; k < 256; ++k) s += pp[k << 6];
    xgs[bb][c] = s;
  }
  if (smr_part && t < 4) {
    const float* sp = smr_part + (t << 8);
    float s = 0.f;
    for (int k = 0; k < 256; ++k) s += sp[k];
    smrs[t] = s;
  }
  __syncthreads();
  {
    int bb = t >> 6, c = t & 63;
    float v = xgs[bb][c];
    if (smr_part) v = (v - lnw[c] * smrs[bb]) * (1.f / 65536.f) + lnb[c];
    else          v = v * (1.f / 65536.f);
    xgs[bb][c] = v;
  }
  __syncthreads();
  if (t < 64) {
    int b = t >> 4, j = t & 15;
    float a = b1[j];
    for (int c = 0; c < 64; ++c) a += w1[j * 80 + c] * xgs[b][c];
    for (int k = 0; k < 16; ++k) a += w1[j * 80 + 64 + k] * hid[b * 16 + k];
    float g = 0.5f * a * (1.f + erff(a * 0.70710678f));   // exact gelu
    h1s[b][j] = g;
    h1_out[b * 16 + j] = g;
    if (out_hidden) out_hidden[b * 16 + j] = g;
  }
  __syncthreads();
  if (t < 12) {
    int b = t / 3, e = t % 3;
    float a = b3[e];
    for (int j = 0; j < 16; ++j) a += w3[e * 16 + j] * h1s[b][j];
    a = fmaxf(a, 0.f);
    logit_out[b * 3 + e] = a;
    out_logits[b * 6 + e * 2 + slot] = a;
  }
}

// ---------------- per (b,expert): softmax(q̂·k̂·temp) -> Weff = P @ Wv ----------------
__global__ void k_expw(const float* __restrict__ M, const float* __restrict__ qkv,
                       const float* __restrict__ temp, float* __restrict__ Weff) {
  int b = blockIdx.x / 3, e = blockIdx.x % 3;
  __shared__ float Ms[64][64];
  __shared__ float TQ[64][64];
  __shared__ float TK[64][64];
  __shared__ float P[64][4];
  __shared__ float nq[64], nk[64];
  const float* W = qkv + e * 12288;
  for (int idx = threadIdx.x; idx < 4096; idx += 256)
    Ms[idx >> 6][idx & 63] = M[b * 4096 + idx];
  __syncthreads();
  {
    int r = threadIdx.x >> 2;
    int v0 = (threadIdx.x & 3) << 4;
    float aq[16] = {}, ak[16] = {};
    for (int u = 0; u < 64; ++u) {
      float wq = W[r * 64 + u];
      float wk = W[(64 + r) * 64 + u];
      #pragma unroll
      for (int i = 0; i < 16; ++i) {
        float m = Ms[u][v0 + i];
        aq[i] += wq * m; ak[i] += wk * m;
      }
    }
    #pragma unroll
    for (int i = 0; i < 16; ++i) { TQ[r][v0 + i] = aq[i]; TK[r][v0 + i] = ak[i]; }
  }
  __syncthreads();
  if (threadIdx.x < 64) {
    int c = threadIdx.x;
    float sq = 0.f, sk = 0.f;
    for (int v = 0; v < 64; ++v) {
      sq += TQ[c][v] * W[c * 64 + v];
      sk += TK[c][v] * W[(64 + c) * 64 + v];
    }
    nq[c] = fmaxf(sqrtf(fmaxf(sq, 0.f)), 1e-12f);
    nk[c] = fmaxf(sqrtf(fmaxf(sk, 0.f)), 1e-12f);
  }
  __syncthreads();
  if (threadIdx.x < 64) {
    int rr = threadIdx.x, h = rr >> 2;
    float tp = temp[e * 16 + h];
    float s[4];
    #pragma unroll
    for (int d = 0; d < 4; ++d) {
      int kc = h * 4 + d;
      float g = 0.f;
      for (int v = 0; v < 64; ++v) g += TQ[rr][v] * W[(64 + kc) * 64 + v];
      s[d] = g / (nq[rr] * nk[kc]) * tp;
    }
    float mx = fmaxf(fmaxf(s[0], s[1]), fmaxf(s[2], s[3]));
    float es[4], sum = 0.f;
    #pragma unroll
    for (int d = 0; d < 4; ++d) { es[d] = __expf(s[d] - mx); sum += es[d]; }
    float inv = 1.f / sum;
    #pragma unroll
    for (int d = 0; d < 4; ++d) P[rr][d] = es[d] * inv;
  }
  __syncthreads();
  if (threadIdx.x < 64) {
    int rr = threadIdx.x, h = rr >> 2;
    for (int u = 0; u < 64; ++u) {
      float a = 0.f;
      #pragma unroll
      for (int d = 0; d < 4; ++d)
        a += P[rr][d] * W[(128 + h * 4 + d) * 64 + u];
      Weff[(size_t)(b * 3 + e) * 4096 + rr * 64 + u] = a;
    }
  }
}

// ------ Ktb[b][tap][o][u] = bf16( Σ_e l1_e Proj_e[o,c] dw_e[c,tap] Weff_e[c,u] ) ------
__global__ void k_kmat(const float* __restrict__ Weff, const float* __restrict__ dw,
                       const float* __restrict__ proj, const float* __restrict__ l1,
                       unsigned short* __restrict__ Ktb) {
  int b = blockIdx.x / 9, t = blockIdx.x % 9;
  __shared__ float S[64][68];
  __shared__ float Pr[64][68];
  int u = threadIdx.x >> 2, o0 = (threadIdx.x & 3) << 4;
  float acc[16] = {};
  for (int e = 0; e < 3; ++e) {
    __syncthreads();
    float le = l1[b * 3 + e];
    for (int idx = threadIdx.x; idx < 4096; idx += 256) {
      int c = idx >> 6, uu = idx & 63;
      S[c][uu] = le * dw[(e * 64 + c) * 9 + t] *
                 Weff[(size_t)(b * 3 + e) * 4096 + c * 64 + uu];
      Pr[c][uu] = proj[e * 4096 + uu * 64 + c];
    }
    __syncthreads();
    for (int c = 0; c < 64; ++c) {
      float sv = S[c][u];
      #pragma unroll
      for (int i = 0; i < 16; ++i) acc[i] += Pr[c][o0 + i] * sv;
    }
  }
  #pragma unroll
  for (int i = 0; i < 16; ++i)
    Ktb[(size_t)(b * 9 + t) * 4096 + (o0 + i) * 64 + u] = f2bs(acc[i]);
}

// -------- MFMA conv (channel-split halo, XCD-chunked swizzle) + residual (reg-stash)
//          + fused LN2 stats/xg2 (no atomics) --------
__global__ __launch_bounds__(256, 4)
void k_conv(const float* __restrict__ x, const float* __restrict__ mu,
            const float* __restrict__ rs, const float* __restrict__ lw,
            const float* __restrict__ lb, const unsigned short* __restrict__ Ktb,
            const float* __restrict__ beta, float* __restrict__ out1,
            const float* __restrict__ lw2, const float* __restrict__ lb2,
            float* __restrict__ mu2, float* __restrict__ rs2,
            float* __restrict__ part2, float* __restrict__ smr_part) {
  __shared__ __align__(16) short lds[16896];
  __shared__ float rsL[256];
  __shared__ float wred[4];

  int tile = ((blockIdx.x & 7) << 7) + (blockIdx.x >> 3);  // bijective, 1024%8==0
  int bx = tile & 15, by = (tile >> 4) & 15, b = tile >> 8;
  int x0 = bx << 4, y0 = by << 4;
  int pb = tile;                                  // == (b<<8)|(by<<4)|bx
  int t = threadIdx.x;
  int w = t >> 6, l = t & 63, l15 = l & 15, g = l >> 4;

  int py = t >> 4, px = t & 15;
  int n_t = ((y0 + py) << 8) + x0 + px;
  int hpt = (py + 1) * 18 + (px + 1);
  float m1 = mu[(b << 16) + n_t], r1 = rs[(b << 16) + n_t];

  f32x4 acc[4][4] = {};
  const unsigned short* Kb = Ktb + (size_t)b * 36864;
  short8 xst[8];                                  // raw x stash (bf16), all indices static

  #pragma unroll
  for (int h = 0; h < 2; ++h) {
    int c0 = h << 5;
    #pragma unroll
    for (int cb = 0; cb < 4; ++cb) {
      short8 pk, xr;
      #pragma unroll
      for (int i = 0; i < 8; ++i) {
        int c = c0 + (cb << 3) + i;
        float xv = x[((size_t)(b * 64 + c) << 16) + n_t];
        xr[i] = (short)f2bs(xv);
        pk[i] = (short)f2bs((xv - m1) * r1 * lw[c] + lb[c]);
      }
      xst[(h << 2) + cb] = xr;
      *(short8*)(lds + hpt * 32 + ((cb ^ (hpt & 3)) << 3)) = pk;
    }
    for (int idx = t; idx < 2176; idx += 256) {
      int bp = idx >> 5, cc = idx & 31;
      int hy, hx;
      if (bp < 18)      { hy = 0;  hx = bp; }
      else if (bp < 36) { hy = 17; hx = bp - 18; }
      else { int r2 = bp - 36; hy = 1 + (r2 >> 1); hx = (r2 & 1) ? 17 : 0; }
      int gy = y0 + hy - 1, gx = x0 + hx - 1;
      float v = 0.f;
      int c = c0 + cc;
      if ((unsigned)gy < 256u && (unsigned)gx < 256u) {
        int n = (gy << 8) + gx;
        v = (x[((size_t)(b * 64 + c) << 16) + n] - mu[(b << 16) + n]) *
            rs[(b << 16) + n] * lw[c] + lb[c];
      }
      int hp = hy * 18 + hx;
      lds[hp * 32 + (((cc >> 3) ^ (hp & 3)) << 3) + (cc & 7)] = (short)f2bs(v);
    }
    __syncthreads();
    int ky = 0, kx = 0;
    #pragma unroll 1
    for (int tap = 0; tap < 9; ++tap) {
      const unsigned short* Kt = Kb + (tap << 12);
      short8 bfr[4];
      #pragma unroll
      for (int ot = 0; ot < 4; ++ot)
        bfr[ot] = *(const short8*)(Kt + (((ot << 4) + l15) << 6) + c0 + (g << 3));
      #pragma unroll
      for (int mi = 0; mi < 4; ++mi) {
        int hp = ((w << 2) + mi + ky) * 18 + l15 + kx;
        short8 af = *(const short8*)(lds + hp * 32 + ((g ^ (hp & 3)) << 3));
        #pragma unroll
        for (int ot = 0; ot < 4; ++ot)
          acc[mi][ot] = __builtin_amdgcn_mfma_f32_16x16x32_bf16(af, bfr[ot], acc[mi][ot], 0, 0, 0);
      }
      if (++kx == 3) { kx = 0; ++ky; }
    }
    __syncthreads();
  }

  #pragma unroll
  for (int mi = 0; mi < 4; ++mi) {
    int p0 = (((w << 2) + mi) << 4) + (g << 2);
    #pragma unroll
    for (int ot = 0; ot < 4; ++ot) {
      int o = (ot << 4) + l15;
      short4 pk;
      pk.x = (short)f2bs(acc[mi][ot][0]);
      pk.y = (short)f2bs(acc[mi][ot][1]);
      pk.z = (short)f2bs(acc[mi][ot][2]);
      pk.w = (short)f2bs(acc[mi][ot][3]);
      *(short4*)(lds + o * 264 + p0) = pk;
    }
  }
  __syncthreads();

  // phase A: residual (from reg stash) + store + LN2 stats (thread owns pixel t)
  float s = 0.f, s2 = 0.f;
  #pragma unroll
  for (int c = 0; c < 64; ++c) {
    size_t gi = ((size_t)(b * 64 + c) << 16) + n_t;
    float v = s2f(lds[c * 264 + t]) + beta[c] * s2f(xst[c >> 3][c & 7]);
    out1[gi] = v;
    s += v; s2 += v * v;
    lds[c * 264 + t] = (short)f2bs(v);           // own column only
  }
  float m = s * 0.015625f;
  float var = s2 * 0.015625f - m * m;
  float rstd = rsqrtf(var + 1e-5f);
  mu2[(b << 16) + n_t] = m;
  rs2[(b << 16) + n_t] = rstd;
  rsL[t] = rstd;
  float mr = m * rstd;
  #pragma unroll
  for (int o = 32; o > 0; o >>= 1) mr += __shfl_down(mr, o, 64);
  if (l == 0) wred[w] = mr;
  __syncthreads();
  if (t == 0) smr_part[pb] = wred[0] + wred[1] + wred[2] + wred[3];

  // phase B: per-channel Σ v·rstd -> 4-lane combine -> ONE plain store
  int cB = t >> 2, qB = t & 3;
  float sv = 0.f;
  #pragma unroll
  for (int i = 0; i < 8; ++i) {
    short8 vv = *(const short8*)(lds + cB * 264 + (qB << 6) + (i << 3));
    #pragma unroll
    for (int j = 0; j < 8; ++j) sv += s2f(vv[j]) * rsL[(qB << 6) + (i << 3) + j];
  }
  sv += __shfl_xor(sv, 1, 64);
  sv += __shfl_xor(sv, 2, 64);
  if (qB == 0) part2[pb * 64 + cB] = sv * lw2[cB];
}

// ------ prep MLP weights PRE-SWIZZLED to per-lane load order ------
__global__ void k_prep(const float* __restrict__ w1_0, const float* __restrict__ w1_1,
                       const float* __restrict__ w1_2,
                       const float* __restrict__ b1_0, const float* __restrict__ b1_1,
                       const float* __restrict__ b1_2,
                       const float* __restrict__ w2_0, const float* __restrict__ w2_1,
                       const float* __restrict__ w2_2,
                       const float* __restrict__ l2,
                       unsigned short* __restrict__ w1x, unsigned short* __restrict__ w2x4,
                       float* __restrict__ b1f) {
  int idx = blockIdx.x * 256 + threadIdx.x;
  if (idx >= 28672) return;
  int instr = idx >> 9, r = idx & 511;
  int li = r >> 3, i = r & 7;
  int l15 = li & 15, g = li >> 4;
  // ---- w1x ----
  {
    int jb = instr >> 2, q = (instr >> 1) & 1, ks = instr & 1;
    int jt = jb * 32 + ((l15 >> 2) << 3) + (l15 & 3) + (q << 2);
    int c = (ks << 5) + (g << 3) + i;
    int e, j;
    if (jt < 64)       { e = 0; j = jt; }
    else if (jt < 192) { e = 1; j = jt - 64; }
    else               { e = 2; j = jt - 192; }
    const float* w1 = e == 0 ? w1_0 : (e == 1 ? w1_1 : w1_2);
    w1x[idx] = f2bs(w1[j * 64 + c]);
  }
  // ---- w2x4 (4 batches, l2 pre-scaled) ----
  {
    int jb = instr >> 2, ot = instr & 3;
    int o = (ot << 4) + l15;
    int j = jb * 32 + (g << 3) + i;
    int e, jj;
    if (j < 64)       { e = 0; jj = j; }
    else if (j < 192) { e = 1; jj = j - 64; }
    else              { e = 2; jj = j - 192; }
    const float* w2 = e == 0 ? w2_0 : (e == 1 ? w2_1 : w2_2);
    int hf = 64 << e;
    float v = w2[o * hf + jj];
    #pragma unroll
    for (int bb = 0; bb < 4; ++bb)
      w2x4[bb * 28672 + idx] = f2bs(v * l2[bb * 3 + e]);
  }
  // ---- b1f ----
  if (idx < 448) {
    int jt = idx, e, j;
    if (jt < 64)       { e = 0; j = jt; }
    else if (jt < 192) { e = 1; j = jt - 64; }
    else               { e = 2; j = jt - 192; }
    const float* b1 = e == 0 ? b1_0 : (e == 1 ? b1_1 : b1_2);
    b1f[jt] = b1[j];
  }
}

// ---------------- MFMA fused MLP bank, LDS-free, raw-intrinsic gelu ----------------
__global__ __launch_bounds__(256, 3)
void k_mlp(float* io,
           const float* __restrict__ mu2, const float* __restrict__ rs2,
           const float* __restrict__ lw, const float* __restrict__ lb,
           const unsigned short* __restrict__ w1x, const unsigned short* __restrict__ w2x4,
           const float* __restrict__ b1f,
           const float* __restrict__ b2_0, const float* __restrict__ b2_1,
           const float* __restrict__ b2_2,
           const float* __restrict__ gamma, const float* __restrict__ l2) {
  int b  = blockIdx.x >> 9;
  int n0 = (blockIdx.x & 511) << 7;
  int t  = threadIdx.x;
  int w  = t >> 6, l = t & 63;
  int l15 = l & 15, g = l >> 4;

  size_t iob = ((size_t)b << 22) + n0;
  float l2v0 = l2[b * 3], l2v1 = l2[b * 3 + 1], l2v2 = l2[b * 3 + 2];
  const unsigned short* w2b = w2x4 + b * 28672;

  short8 xf[2][2];
  #pragma unroll
  for (int pf = 0; pf < 2; ++pf) {
    int pl = (w << 5) + (pf << 4) + l15;
    float muv = mu2[(b << 16) + n0 + pl];
    float rsv = rs2[(b << 16) + n0 + pl];
    #pragma unroll
    for (int ks = 0; ks < 2; ++ks)
      #pragma unroll
      for (int i = 0; i < 8; ++i) {
        int c = (ks << 5) + (g << 3) + i;
        float v = (io[iob + ((size_t)c << 16) + pl] - muv) * rsv * lw[c] + lb[c];
        xf[pf][ks][i] = (short)f2bs(v);
      }
  }

  f32x4 acc2[2][4] = {{{0,0,0,0},{0,0,0,0},{0,0,0,0},{0,0,0,0}},
                      {{0,0,0,0},{0,0,0,0},{0,0,0,0},{0,0,0,0}}};

  const float GA = -2.3022081f;   // -2*log2(e)*0.7978845608
  const float GB = -0.1029437f;   // -2*log2(e)*0.0356774081

  #pragma unroll 2
  for (int jb = 0; jb < 14; ++jb) {
    int j0 = jb << 5;
    short8 w1a[2][2];
    f32x4 b1v[2];
    #pragma unroll
    for (int q = 0; q < 2; ++q) {
      int ibase = ((jb << 1) | q) << 1;
      w1a[q][0] = *(const short8*)(w1x + ((ibase | 0) << 9) + (l << 3));
      w1a[q][1] = *(const short8*)(w1x + ((ibase | 1) << 9) + (l << 3));
      b1v[q] = *(const f32x4*)(b1f + j0 + (g << 3) + (q << 2));
    }
    short8 A2[2];
    #pragma unroll
    for (int pf = 0; pf < 2; ++pf) {
      #pragma unroll
      for (int q = 0; q < 2; ++q) {
        f32x4 d1 = {0.f, 0.f, 0.f, 0.f};
        d1 = __builtin_amdgcn_mfma_f32_16x16x32_bf16(w1a[q][0], xf[pf][0], d1, 0, 0, 0);
        d1 = __builtin_amdgcn_mfma_f32_16x16x32_bf16(w1a[q][1], xf[pf][1], d1, 0, 0, 0);
        #pragma unroll
        for (int r = 0; r < 4; ++r) {
          float tv = d1[r] + b1v[q][r];
          float t2 = tv * tv;
          float arg = tv * (GA + GB * t2);
          float e1 = __builtin_amdgcn_exp2f(arg);           // raw v_exp_f32
          float gv = tv * __builtin_amdgcn_rcpf(1.f + e1);  // raw v_rcp_f32
          A2[pf][(q << 2) + r] = (short)f2bs(gv);
        }
      }
    }
    #pragma unroll
    for (int ot = 0; ot < 4; ++ot) {
      short8 w2f = *(const short8*)(w2b + (((jb << 2) | ot) << 9) + (l << 3));
      acc2[0][ot] = __builtin_amdgcn_mfma_f32_16x16x32_bf16(A2[0], w2f, acc2[0][ot], 0, 0, 0);
      acc2[1][ot] = __builtin_amdgcn_mfma_f32_16x16x32_bf16(A2[1], w2f, acc2[1][ot], 0, 0, 0);
    }
  }

  #pragma unroll
  for (int ot = 0; ot < 4; ++ot) {
    int o = (ot << 4) + l15;
    float bias = l2v0 * b2_0[o] + l2v1 * b2_1[o] + l2v2 * b2_2[o];
    float gmv = gamma[o];
    #pragma unroll
    for (int pf = 0; pf < 2; ++pf) {
      int p0 = (w << 5) + (pf << 4) + (g << 2);
      float* gp = io + iob + ((size_t)o << 16) + p0;
      f32x4 old = *(const f32x4*)gp;
      f32x4 res;
      #pragma unroll
      for (int r = 0; r < 4; ++r)
        res[r] = acc2[pf][ot][r] + gmv * old[r] + bias;
      *(f32x4*)gp = res;
    }
  }
}

extern "C" void kernel_launch(void* const* d_in, const int* in_sizes, int n_in,
                              void* d_out, int out_size, void* d_ws, size_t ws_size,
                              hipStream_t stream) {
  (void)in_sizes; (void)n_in; (void)out_size; (void)ws_size;
  const float* x        = (const float*)d_in[0];
  const float* hidden   = (const float*)d_in[1];
  const float* ln1_w    = (const float*)d_in[2];
  const float* ln1_b    = (const float*)d_in[3];
  const float* ln2_w    = (const float*)d_in[4];
  const float* ln2_b    = (const float*)d_in[5];
  const float* beta     = (const float*)d_in[6];
  const float* gamma    = (const float*)d_in[7];
  const float* att_temp = (const float*)d_in[8];
  const float* att_qkv  = (const float*)d_in[9];
  const float* att_dw   = (const float*)d_in[10];
  const float* att_proj = (const float*)d_in[11];
  const float* ar1_w    = (const float*)d_in[12];
  const float* ar1_b    = (const float*)d_in[13];
  const float* ar3_w    = (const float*)d_in[14];
  const float* ar3_b    = (const float*)d_in[15];
  const float* mr1_w    = (const float*)d_in[16];
  const float* mr1_b    = (const float*)d_in[17];
  const float* mr3_w    = (const float*)d_in[18];
  const float* mr3_b    = (const float*)d_in[19];
  const float* w1s[3] = {(const float*)d_in[20], (const float*)d_in[24], (const float*)d_in[28]};
  const float* b1s[3] = {(const float*)d_in[21], (const float*)d_in[25], (const float*)d_in[29]};
  const float* w2s[3] = {(const float*)d_in[22], (const float*)d_in[26], (const float*)d_in[30]};
  const float* b2s[3] = {(const float*)d_in[23], (const float*)d_in[27], (const float*)d_in[31]};

  // ---- workspace (~5.6 MB fp32) ----
  float* F    = (float*)d_ws;
  float* mu1  = F + 0;          // 262144
  float* rs1  = F + 262144;     // 262144
  float* mu2  = F + 524288;     // 262144
  float* rs2  = F + 786432;     // 262144
  float* M    = F + 1048576;    // 16384  (zeroed)
  float* part1= F + 1064960;    // 65536
  float* part2= F + 1130496;    // 65536
  float* smrp = F + 1196032;    // 1024
  float* h1a  = F + 1197056;    // 64
  float* h1m  = F + 1197120;    // 64
  float* l1   = F + 1197184;    // 16
  float* l2   = F + 1197200;    // 16
  float* Weff = F + 1197216;    // 49152
  unsigned short* Ktb = (unsigned short*)(F + 1246368);   // 147456 ushorts
  float* b1f  = F + 1320096;    // 448
  unsigned short* w1x  = (unsigned short*)(F + 1320544);  // 28672 ushorts
  unsigned short* w2x4 = (unsigned short*)(F + 1334880);  // 114688 ushorts

  float* out_main   = (float*)d_out;             // holds out1 between banks
  float* out_hidden = out_main + 16777216;
  float* out_logits = out_main + 16777280;

  // ---- attention bank ----
  k_zero   <<<64, 256, 0, stream>>>(M, 16384);
  k_statsxg<<<1024, 256, 0, stream>>>(x, mu1, rs1, ln1_w, ln1_b, part1, M);
  k_route  <<<1, 256, 0, stream>>>(part1, nullptr, ln1_w, ln1_b, hidden,
                                   ar1_w, ar1_b, ar3_w, ar3_b,
                                   h1a, l1, out_logits, 0, nullptr);
  k_expw   <<<12, 256, 0, stream>>>(M, att_qkv, att_temp, Weff);
  k_kmat   <<<36, 256, 0, stream>>>(Weff, att_dw, att_proj, l1, Ktb);
  k_conv   <<<1024, 256, 0, stream>>>(x, mu1, rs1, ln1_w, ln1_b, Ktb,
                                      beta, out_main, ln2_w, ln2_b,
                                      mu2, rs2, part2, smrp);
  // ---- MLP bank (out1 lives in d_out) ----
  k_route  <<<1, 256, 0, stream>>>(part2, smrp, ln2_w, ln2_b, h1a,
                                   mr1_w, mr1_b, mr3_w, mr3_b,
                                   h1m, l2, out_logits, 1, out_hidden);
  k_prep   <<<112, 256, 0, stream>>>(w1s[0], w1s[1], w1s[2], b1s[0], b1s[1], b1s[2],
                                     w2s[0], w2s[1], w2s[2], l2, w1x, w2x4, b1f);
  k_mlp    <<<2048, 256, 0, stream>>>(out_main, mu2, rs2, ln2_w, ln2_b,
                                      w1x, w2x4, b1f, b2s[0], b2s[1], b2s[2],
                                      gamma, l2);
}

// Round 19
// 247.201 us; speedup vs baseline: 1.0150x; 1.0150x over previous
//
#include <hip/hip_runtime.h>
#include <hip/hip_bf16.h>
#include <cstddef>

typedef __attribute__((ext_vector_type(8))) short short8;
typedef __attribute__((ext_vector_type(4))) float f32x4;

#define NPIX 65536  // 256*256

static __device__ __forceinline__ unsigned short f2bs(float f) {
  __hip_bfloat16 h = __float2bfloat16(f);
  return __builtin_bit_cast(unsigned short, h);
}
static __device__ __forceinline__ float s2f(short s) {
  union { unsigned u; float f; } v; v.u = ((unsigned)(unsigned short)s) << 16;
  return v.f;
}

__global__ void k_zero(float* __restrict__ p, int n) {
  int i = blockIdx.x * 256 + threadIdx.x;
  if (i < n) p[i] = 0.f;
}

// ---- fused bank-1 pre-pass: mu1/rs1 per pixel, xg1 partial sums (no atomics), Gram M ----
__global__ __launch_bounds__(256, 4)
void k_statsxg(const float* __restrict__ in, float* __restrict__ mu,
               float* __restrict__ rs, const float* __restrict__ lnw,
               const float* __restrict__ lnb, float* __restrict__ part1,
               float* __restrict__ M) {
  __shared__ __align__(16) short tile[64 * 264];   // [c][256 px + pad]
  int t = threadIdx.x;
  int pi = blockIdx.x * 256 + t;
  int b = blockIdx.x >> 8;
  const float* p = in + ((size_t)b << 22) + (pi & 65535);
  float s = 0.f, s2 = 0.f;
  #pragma unroll
  for (int c = 0; c < 64; ++c) {
    float v = p[(size_t)c << 16];
    s += v; s2 += v * v;
    tile[c * 264 + t] = (short)f2bs(v);
  }
  float m = s * 0.015625f;
  float var = s2 * 0.015625f - m * m;
  float rstd = rsqrtf(var + 1e-5f);
  mu[pi] = m; rs[pi] = rstd;
  #pragma unroll
  for (int c = 0; c < 64; ++c) {
    float lnv = (s2f(tile[c * 264 + t]) - m) * rstd * lnw[c] + lnb[c];
    tile[c * 264 + t] = (short)f2bs(lnv);          // own column only
  }
  __syncthreads();
  // per-channel row sums -> 4-lane combine -> ONE plain store per (block, channel)
  {
    int cB = t >> 2, qB = t & 3;
    float rsum = 0.f;
    #pragma unroll
    for (int i = 0; i < 8; ++i) {
      short8 vv = *(const short8*)(tile + cB * 264 + (qB << 6) + (i << 3));
      #pragma unroll
      for (int j = 0; j < 8; ++j) rsum += s2f(vv[j]);
    }
    rsum += __shfl_xor(rsum, 1, 64);
    rsum += __shfl_xor(rsum, 2, 64);
    if (qB == 0) part1[blockIdx.x * 64 + cB] = rsum;
  }
  // Gram: wave w computes rows 16w..16w+15 x all 64 cols, K = 256 px
  int l = t & 63, w = t >> 6, l15 = l & 15, g = l >> 4;
  f32x4 ga[4] = {{0,0,0,0},{0,0,0,0},{0,0,0,0},{0,0,0,0}};
  #pragma unroll
  for (int kt = 0; kt < 8; ++kt) {
    short8 af = *(const short8*)(tile + (16 * w + l15) * 264 + (kt << 5) + (g << 3));
    #pragma unroll
    for (int ot = 0; ot < 4; ++ot) {
      short8 bfg = *(const short8*)(tile + ((ot << 4) + l15) * 264 + (kt << 5) + (g << 3));
      ga[ot] = __builtin_amdgcn_mfma_f32_16x16x32_bf16(af, bfg, ga[ot], 0, 0, 0);
    }
  }
  float* Mb = M + b * 4096;
  #pragma unroll
  for (int ot = 0; ot < 4; ++ot)
    #pragma unroll
    for (int r = 0; r < 4; ++r)
      atomicAdd(&Mb[(16 * w + (g << 2) + r) * 64 + (ot << 4) + l15], ga[ot][r]);
}

// ---------------- routing (256 thr): reduce 256 partials/(b,c), then route ----------------
__global__ __launch_bounds__(256)
void k_route(const float* __restrict__ part, const float* __restrict__ smr_part,
             const float* __restrict__ lnw, const float* __restrict__ lnb,
             const float* __restrict__ hid,
             const float* __restrict__ w1, const float* __restrict__ b1,
             const float* __restrict__ w3, const float* __restrict__ b3,
             float* __restrict__ h1_out, float* __restrict__ logit_out,
             float* __restrict__ out_logits, int slot,
             float* __restrict__ out_hidden) {
  __shared__ float xgs[4][64];
  __shared__ float smrs[4];
  __shared__ float h1s[4][16];
  int t = threadIdx.x;                             // 256 threads
  {
    int bb = t >> 6, c = t & 63;
    const float* pp = part + (bb << 14) + c;
    float s = 0.f;
    for (int k = 0; k < 256; ++k) s += pp[k << 6];
    xgs[bb][c] = s;
  }
  if (smr_part && t < 4) {
    const float* sp = smr_part + (t << 8);
    float s = 0.f;
    for (int k = 0; k < 256; ++k) s += sp[k];
    smrs[t] = s;
  }
  __syncthreads();
  {
    int bb = t >> 6, c = t & 63;
    float v = xgs[bb][c];
    if (smr_part) v = (v - lnw[c] * smrs[bb]) * (1.f / 65536.f) + lnb[c];
    else          v = v * (1.f / 65536.f);
    xgs[bb][c] = v;
  }
  __syncthreads();
  if (t < 64) {
    int b = t >> 4, j = t & 15;
    float a = b1[j];
    for (int c = 0; c < 64; ++c) a += w1[j * 80 + c] * xgs[b][c];
    for (int k = 0; k < 16; ++k) a += w1[j * 80 + 64 + k] * hid[b * 16 + k];
    float g = 0.5f * a * (1.f + erff(a * 0.70710678f));   // exact gelu
    h1s[b][j] = g;
    h1_out[b * 16 + j] = g;
    if (out_hidden) out_hidden[b * 16 + j] = g;
  }
  __syncthreads();
  if (t < 12) {
    int b = t / 3, e = t % 3;
    float a = b3[e];
    for (int j = 0; j < 16; ++j) a += w3[e * 16 + j] * h1s[b][j];
    a = fmaxf(a, 0.f);
    logit_out[b * 3 + e] = a;
    out_logits[b * 6 + e * 2 + slot] = a;
  }
}

// ---------------- per (b,expert): softmax(q̂·k̂·temp) -> Weff = P @ Wv ----------------
__global__ void k_expw(const float* __restrict__ M, const float* __restrict__ qkv,
                       const float* __restrict__ temp, float* __restrict__ Weff) {
  int b = blockIdx.x / 3, e = blockIdx.x % 3;
  __shared__ float Ms[64][64];
  __shared__ float TQ[64][64];
  __shared__ float TK[64][64];
  __shared__ float P[64][4];
  __shared__ float nq[64], nk[64];
  const float* W = qkv + e * 12288;
  for (int idx = threadIdx.x; idx < 4096; idx += 256)
    Ms[idx >> 6][idx & 63] = M[b * 4096 + idx];
  __syncthreads();
  {
    int r = threadIdx.x >> 2;
    int v0 = (threadIdx.x & 3) << 4;
    float aq[16] = {}, ak[16] = {};
    for (int u = 0; u < 64; ++u) {
      float wq = W[r * 64 + u];
      float wk = W[(64 + r) * 64 + u];
      #pragma unroll
      for (int i = 0; i < 16; ++i) {
        float m = Ms[u][v0 + i];
        aq[i] += wq * m; ak[i] += wk * m;
      }
    }
    #pragma unroll
    for (int i = 0; i < 16; ++i) { TQ[r][v0 + i] = aq[i]; TK[r][v0 + i] = ak[i]; }
  }
  __syncthreads();
  if (threadIdx.x < 64) {
    int c = threadIdx.x;
    float sq = 0.f, sk = 0.f;
    for (int v = 0; v < 64; ++v) {
      sq += TQ[c][v] * W[c * 64 + v];
      sk += TK[c][v] * W[(64 + c) * 64 + v];
    }
    nq[c] = fmaxf(sqrtf(fmaxf(sq, 0.f)), 1e-12f);
    nk[c] = fmaxf(sqrtf(fmaxf(sk, 0.f)), 1e-12f);
  }
  __syncthreads();
  if (threadIdx.x < 64) {
    int rr = threadIdx.x, h = rr >> 2;
    float tp = temp[e * 16 + h];
    float s[4];
    #pragma unroll
    for (int d = 0; d < 4; ++d) {
      int kc = h * 4 + d;
      float g = 0.f;
      for (int v = 0; v < 64; ++v) g += TQ[rr][v] * W[(64 + kc) * 64 + v];
      s[d] = g / (nq[rr] * nk[kc]) * tp;
    }
    float mx = fmaxf(fmaxf(s[0], s[1]), fmaxf(s[2], s[3]));
    float es[4], sum = 0.f;
    #pragma unroll
    for (int d = 0; d < 4; ++d) { es[d] = __expf(s[d] - mx); sum += es[d]; }
    float inv = 1.f / sum;
    #pragma unroll
    for (int d = 0; d < 4; ++d) P[rr][d] = es[d] * inv;
  }
  __syncthreads();
  if (threadIdx.x < 64) {
    int rr = threadIdx.x, h = rr >> 2;
    for (int u = 0; u < 64; ++u) {
      float a = 0.f;
      #pragma unroll
      for (int d = 0; d < 4; ++d)
        a += P[rr][d] * W[(128 + h * 4 + d) * 64 + u];
      Weff[(size_t)(b * 3 + e) * 4096 + rr * 64 + u] = a;
    }
  }
}

// ------ Ktb[b][tap][o][u] = bf16( Σ_e l1_e Proj_e[o,c] dw_e[c,tap] Weff_e[c,u] ) ------
__global__ void k_kmat(const float* __restrict__ Weff, const float* __restrict__ dw,
                       const float* __restrict__ proj, const float* __restrict__ l1,
                       unsigned short* __restrict__ Ktb) {
  int b = blockIdx.x / 9, t = blockIdx.x % 9;
  __shared__ float S[64][68];
  __shared__ float Pr[64][68];
  int u = threadIdx.x >> 2, o0 = (threadIdx.x & 3) << 4;
  float acc[16] = {};
  for (int e = 0; e < 3; ++e) {
    __syncthreads();
    float le = l1[b * 3 + e];
    for (int idx = threadIdx.x; idx < 4096; idx += 256) {
      int c = idx >> 6, uu = idx & 63;
      S[c][uu] = le * dw[(e * 64 + c) * 9 + t] *
                 Weff[(size_t)(b * 3 + e) * 4096 + c * 64 + uu];
      Pr[c][uu] = proj[e * 4096 + uu * 64 + c];
    }
    __syncthreads();
    for (int c = 0; c < 64; ++c) {
      float sv = S[c][u];
      #pragma unroll
      for (int i = 0; i < 16; ++i) acc[i] += Pr[c][o0 + i] * sv;
    }
  }
  #pragma unroll
  for (int i = 0; i < 16; ++i)
    Ktb[(size_t)(b * 9 + t) * 4096 + (o0 + i) * 64 + u] = f2bs(acc[i]);
}

// -------- MFMA conv (channel-split halo, XCD-chunked swizzle) + residual
//          + fused LN2 stats/xg2 (no atomics) --------
__global__ __launch_bounds__(256, 4)
void k_conv(const float* __restrict__ x, const float* __restrict__ mu,
            const float* __restrict__ rs, const float* __restrict__ lw,
            const float* __restrict__ lb, const unsigned short* __restrict__ Ktb,
            const float* __restrict__ beta, float* __restrict__ out1,
            const float* __restrict__ lw2, const float* __restrict__ lb2,
            float* __restrict__ mu2, float* __restrict__ rs2,
            float* __restrict__ part2, float* __restrict__ smr_part) {
  __shared__ __align__(16) short lds[16896];
  __shared__ float rsL[256];
  __shared__ float wred[4];

  int tile = ((blockIdx.x & 7) << 7) + (blockIdx.x >> 3);  // bijective, 1024%8==0
  int bx = tile & 15, by = (tile >> 4) & 15, b = tile >> 8;
  int x0 = bx << 4, y0 = by << 4;
  int pb = tile;                                  // == (b<<8)|(by<<4)|bx
  int t = threadIdx.x;
  int w = t >> 6, l = t & 63, l15 = l & 15, g = l >> 4;

  int py = t >> 4, px = t & 15;
  int n_t = ((y0 + py) << 8) + x0 + px;
  int hpt = (py + 1) * 18 + (px + 1);
  float m1 = mu[(b << 16) + n_t], r1 = rs[(b << 16) + n_t];

  f32x4 acc[4][4] = {};
  const unsigned short* Kb = Ktb + (size_t)b * 36864;

  #pragma unroll 1
  for (int h = 0; h < 2; ++h) {
    int c0 = h << 5;
    #pragma unroll
    for (int cb = 0; cb < 4; ++cb) {
      short8 pk;
      #pragma unroll
      for (int i = 0; i < 8; ++i) {
        int c = c0 + (cb << 3) + i;
        float xv = x[((size_t)(b * 64 + c) << 16) + n_t];
        pk[i] = (short)f2bs((xv - m1) * r1 * lw[c] + lb[c]);
      }
      *(short8*)(lds + hpt * 32 + ((cb ^ (hpt & 3)) << 3)) = pk;
    }
    for (int idx = t; idx < 2176; idx += 256) {
      int bp = idx >> 5, cc = idx & 31;
      int hy, hx;
      if (bp < 18)      { hy = 0;  hx = bp; }
      else if (bp < 36) { hy = 17; hx = bp - 18; }
      else { int r2 = bp - 36; hy = 1 + (r2 >> 1); hx = (r2 & 1) ? 17 : 0; }
      int gy = y0 + hy - 1, gx = x0 + hx - 1;
      float v = 0.f;
      int c = c0 + cc;
      if ((unsigned)gy < 256u && (unsigned)gx < 256u) {
        int n = (gy << 8) + gx;
        v = (x[((size_t)(b * 64 + c) << 16) + n] - mu[(b << 16) + n]) *
            rs[(b << 16) + n] * lw[c] + lb[c];
      }
      int hp = hy * 18 + hx;
      lds[hp * 32 + (((cc >> 3) ^ (hp & 3)) << 3) + (cc & 7)] = (short)f2bs(v);
    }
    __syncthreads();
    int ky = 0, kx = 0;
    #pragma unroll 1
    for (int tap = 0; tap < 9; ++tap) {
      const unsigned short* Kt = Kb + (tap << 12);
      short8 bfr[4];
      #pragma unroll
      for (int ot = 0; ot < 4; ++ot)
        bfr[ot] = *(const short8*)(Kt + (((ot << 4) + l15) << 6) + c0 + (g << 3));
      #pragma unroll
      for (int mi = 0; mi < 4; ++mi) {
        int hp = ((w << 2) + mi + ky) * 18 + l15 + kx;
        short8 af = *(const short8*)(lds + hp * 32 + ((g ^ (hp & 3)) << 3));
        #pragma unroll
        for (int ot = 0; ot < 4; ++ot)
          acc[mi][ot] = __builtin_amdgcn_mfma_f32_16x16x32_bf16(af, bfr[ot], acc[mi][ot], 0, 0, 0);
      }
      if (++kx == 3) { kx = 0; ++ky; }
    }
    __syncthreads();
  }

  #pragma unroll
  for (int mi = 0; mi < 4; ++mi) {
    int p0 = (((w << 2) + mi) << 4) + (g << 2);
    #pragma unroll
    for (int ot = 0; ot < 4; ++ot) {
      int o = (ot << 4) + l15;
      short4 pk;
      pk.x = (short)f2bs(acc[mi][ot][0]);
      pk.y = (short)f2bs(acc[mi][ot][1]);
      pk.z = (short)f2bs(acc[mi][ot][2]);
      pk.w = (short)f2bs(acc[mi][ot][3]);
      *(short4*)(lds + o * 264 + p0) = pk;
    }
  }
  __syncthreads();

  // phase A: residual + store + LN2 stats (thread owns pixel t)
  float s = 0.f, s2 = 0.f;
  #pragma unroll
  for (int c = 0; c < 64; ++c) {
    size_t gi = ((size_t)(b * 64 + c) << 16) + n_t;
    float v = s2f(lds[c * 264 + t]) + beta[c] * x[gi];
    out1[gi] = v;
    s += v; s2 += v * v;
    lds[c * 264 + t] = (short)f2bs(v);           // own column only
  }
  float m = s * 0.015625f;
  float var = s2 * 0.015625f - m * m;
  float rstd = rsqrtf(var + 1e-5f);
  mu2[(b << 16) + n_t] = m;
  rs2[(b << 16) + n_t] = rstd;
  rsL[t] = rstd;
  float mr = m * rstd;
  #pragma unroll
  for (int o = 32; o > 0; o >>= 1) mr += __shfl_down(mr, o, 64);
  if (l == 0) wred[w] = mr;
  __syncthreads();
  if (t == 0) smr_part[pb] = wred[0] + wred[1] + wred[2] + wred[3];

  // phase B: per-channel Σ v·rstd -> 4-lane combine -> ONE plain store
  int cB = t >> 2, qB = t & 3;
  float sv = 0.f;
  #pragma unroll
  for (int i = 0; i < 8; ++i) {
    short8 vv = *(const short8*)(lds + cB * 264 + (qB << 6) + (i << 3));
    #pragma unroll
    for (int j = 0; j < 8; ++j) sv += s2f(vv[j]) * rsL[(qB << 6) + (i << 3) + j];
  }
  sv += __shfl_xor(sv, 1, 64);
  sv += __shfl_xor(sv, 2, 64);
  if (qB == 0) part2[pb * 64 + cB] = sv * lw2[cB];
}

// ------ prep MLP weights PRE-SWIZZLED to per-lane load order ------
__global__ void k_prep(const float* __restrict__ w1_0, const float* __restrict__ w1_1,
                       const float* __restrict__ w1_2,
                       const float* __restrict__ b1_0, const float* __restrict__ b1_1,
                       const float* __restrict__ b1_2,
                       const float* __restrict__ w2_0, const float* __restrict__ w2_1,
                       const float* __restrict__ w2_2,
                       const float* __restrict__ l2,
                       unsigned short* __restrict__ w1x, unsigned short* __restrict__ w2x4,
                       float* __restrict__ b1f) {
  int idx = blockIdx.x * 256 + threadIdx.x;
  if (idx >= 28672) return;
  int instr = idx >> 9, r = idx & 511;
  int li = r >> 3, i = r & 7;
  int l15 = li & 15, g = li >> 4;
  // ---- w1x ----
  {
    int jb = instr >> 2, q = (instr >> 1) & 1, ks = instr & 1;
    int jt = jb * 32 + ((l15 >> 2) << 3) + (l15 & 3) + (q << 2);
    int c = (ks << 5) + (g << 3) + i;
    int e, j;
    if (jt < 64)       { e = 0; j = jt; }
    else if (jt < 192) { e = 1; j = jt - 64; }
    else               { e = 2; j = jt - 192; }
    const float* w1 = e == 0 ? w1_0 : (e == 1 ? w1_1 : w1_2);
    w1x[idx] = f2bs(w1[j * 64 + c]);
  }
  // ---- w2x4 (4 batches, l2 pre-scaled) ----
  {
    int jb = instr >> 2, ot = instr & 3;
    int o = (ot << 4) + l15;
    int j = jb * 32 + (g << 3) + i;
    int e, jj;
    if (j < 64)       { e = 0; jj = j; }
    else if (j < 192) { e = 1; jj = j - 64; }
    else              { e = 2; jj = j - 192; }
    const float* w2 = e == 0 ? w2_0 : (e == 1 ? w2_1 : w2_2);
    int hf = 64 << e;
    float v = w2[o * hf + jj];
    #pragma unroll
    for (int bb = 0; bb < 4; ++bb)
      w2x4[bb * 28672 + idx] = f2bs(v * l2[bb * 3 + e]);
  }
  // ---- b1f ----
  if (idx < 448) {
    int jt = idx, e, j;
    if (jt < 64)       { e = 0; j = jt; }
    else if (jt < 192) { e = 1; j = jt - 64; }
    else               { e = 2; j = jt - 192; }
    const float* b1 = e == 0 ? b1_0 : (e == 1 ? b1_1 : b1_2);
    b1f[jt] = b1[j];
  }
}

// ---------------- MFMA fused MLP bank, LDS-free, raw-intrinsic gelu ----------------
__global__ __launch_bounds__(256, 3)
void k_mlp(float* io,
           const float* __restrict__ mu2, const float* __restrict__ rs2,
           const float* __restrict__ lw, const float* __restrict__ lb,
           const unsigned short* __restrict__ w1x, const unsigned short* __restrict__ w2x4,
           const float* __restrict__ b1f,
           const float* __restrict__ b2_0, const float* __restrict__ b2_1,
           const float* __restrict__ b2_2,
           const float* __restrict__ gamma, const float* __restrict__ l2) {
  int b  = blockIdx.x >> 9;
  int n0 = (blockIdx.x & 511) << 7;
  int t  = threadIdx.x;
  int w  = t >> 6, l = t & 63;
  int l15 = l & 15, g = l >> 4;

  size_t iob = ((size_t)b << 22) + n0;
  float l2v0 = l2[b * 3], l2v1 = l2[b * 3 + 1], l2v2 = l2[b * 3 + 2];
  const unsigned short* w2b = w2x4 + b * 28672;

  short8 xf[2][2];
  #pragma unroll
  for (int pf = 0; pf < 2; ++pf) {
    int pl = (w << 5) + (pf << 4) + l15;
    float muv = mu2[(b << 16) + n0 + pl];
    float rsv = rs2[(b << 16) + n0 + pl];
    #pragma unroll
    for (int ks = 0; ks < 2; ++ks)
      #pragma unroll
      for (int i = 0; i < 8; ++i) {
        int c = (ks << 5) + (g << 3) + i;
        float v = (io[iob + ((size_t)c << 16) + pl] - muv) * rsv * lw[c] + lb[c];
        xf[pf][ks][i] = (short)f2bs(v);
      }
  }

  f32x4 acc2[2][4] = {{{0,0,0,0},{0,0,0,0},{0,0,0,0},{0,0,0,0}},
                      {{0,0,0,0},{0,0,0,0},{0,0,0,0},{0,0,0,0}}};

  const float GA = -2.3022081f;   // -2*log2(e)*0.7978845608
  const float GB = -0.1029437f;   // -2*log2(e)*0.0356774081

  #pragma unroll 2
  for (int jb = 0; jb < 14; ++jb) {
    int j0 = jb << 5;
    short8 w1a[2][2];
    f32x4 b1v[2];
    #pragma unroll
    for (int q = 0; q < 2; ++q) {
      int ibase = ((jb << 1) | q) << 1;
      w1a[q][0] = *(const short8*)(w1x + ((ibase | 0) << 9) + (l << 3));
      w1a[q][1] = *(const short8*)(w1x + ((ibase | 1) << 9) + (l << 3));
      b1v[q] = *(const f32x4*)(b1f + j0 + (g << 3) + (q << 2));
    }
    short8 A2[2];
    #pragma unroll
    for (int pf = 0; pf < 2; ++pf) {
      #pragma unroll
      for (int q = 0; q < 2; ++q) {
        f32x4 d1 = {0.f, 0.f, 0.f, 0.f};
        d1 = __builtin_amdgcn_mfma_f32_16x16x32_bf16(w1a[q][0], xf[pf][0], d1, 0, 0, 0);
        d1 = __builtin_amdgcn_mfma_f32_16x16x32_bf16(w1a[q][1], xf[pf][1], d1, 0, 0, 0);
        #pragma unroll
        for (int r = 0; r < 4; ++r) {
          float tv = d1[r] + b1v[q][r];
          float t2 = tv * tv;
          float arg = tv * (GA + GB * t2);
          float e1 = __builtin_amdgcn_exp2f(arg);           // raw v_exp_f32
          float gv = tv * __builtin_amdgcn_rcpf(1.f + e1);  // raw v_rcp_f32
          A2[pf][(q << 2) + r] = (short)f2bs(gv);
        }
      }
    }
    #pragma unroll
    for (int ot = 0; ot < 4; ++ot) {
      short8 w2f = *(const short8*)(w2b + (((jb << 2) | ot) << 9) + (l << 3));
      acc2[0][ot] = __builtin_amdgcn_mfma_f32_16x16x32_bf16(A2[0], w2f, acc2[0][ot], 0, 0, 0);
      acc2[1][ot] = __builtin_amdgcn_mfma_f32_16x16x32_bf16(A2[1], w2f, acc2[1][ot], 0, 0, 0);
    }
  }

  #pragma unroll
  for (int ot = 0; ot < 4; ++ot) {
    int o = (ot << 4) + l15;
    float bias = l2v0 * b2_0[o] + l2v1 * b2_1[o] + l2v2 * b2_2[o];
    float gmv = gamma[o];
    #pragma unroll
    for (int pf = 0; pf < 2; ++pf) {
      int p0 = (w << 5) + (pf << 4) + (g << 2);
      float* gp = io + iob + ((size_t)o << 16) + p0;
      f32x4 old = *(const f32x4*)gp;
      f32x4 res;
      #pragma unroll
      for (int r = 0; r < 4; ++r)
        res[r] = acc2[pf][ot][r] + gmv * old[r] + bias;
      *(f32x4*)gp = res;
    }
  }
}

extern "C" void kernel_launch(void* const* d_in, const int* in_sizes, int n_in,
                              void* d_out, int out_size, void* d_ws, size_t ws_size,
                              hipStream_t stream) {
  (void)in_sizes; (void)n_in; (void)out_size; (void)ws_size;
  const float* x        = (const float*)d_in[0];
  const float* hidden   = (const float*)d_in[1];
  const float* ln1_w    = (const float*)d_in[2];
  const float* ln1_b    = (const float*)d_in[3];
  const float* ln2_w    = (const float*)d_in[4];
  const float* ln2_b    = (const float*)d_in[5];
  const float* beta     = (const float*)d_in[6];
  const float* gamma    = (const float*)d_in[7];
  const float* att_temp = (const float*)d_in[8];
  const float* att_qkv  = (const float*)d_in[9];
  const float* att_dw   = (const float*)d_in[10];
  const float* att_proj = (const float*)d_in[11];
  const float* ar1_w    = (const float*)d_in[12];
  const float* ar1_b    = (const float*)d_in[13];
  const float* ar3_w    = (const float*)d_in[14];
  const float* ar3_b    = (const float*)d_in[15];
  const float* mr1_w    = (const float*)d_in[16];
  const float* mr1_b    = (const float*)d_in[17];
  const float* mr3_w    = (const float*)d_in[18];
  const float* mr3_b    = (const float*)d_in[19];
  const float* w1s[3] = {(const float*)d_in[20], (const float*)d_in[24], (const float*)d_in[28]};
  const float* b1s[3] = {(const float*)d_in[21], (const float*)d_in[25], (const float*)d_in[29]};
  const float* w2s[3] = {(const float*)d_in[22], (const float*)d_in[26], (const float*)d_in[30]};
  const float* b2s[3] = {(const float*)d_in[23], (const float*)d_in[27], (const float*)d_in[31]};

  // ---- workspace (~5.6 MB fp32) ----
  float* F    = (float*)d_ws;
  float* mu1  = F + 0;          // 262144
  float* rs1  = F + 262144;     // 262144
  float* mu2  = F + 524288;     // 262144
  float* rs2  = F + 786432;     // 262144
  float* M    = F + 1048576;    // 16384  (zeroed)
  float* part1= F + 1064960;    // 65536
  float* part2= F + 1130496;    // 65536
  float* smrp = F + 1196032;    // 1024
  float* h1a  = F + 1197056;    // 64
  float* h1m  = F + 1197120;    // 64
  float* l1   = F + 1197184;    // 16
  float* l2   = F + 1197200;    // 16
  float* Weff = F + 1197216;    // 49152
  unsigned short* Ktb = (unsigned short*)(F + 1246368);   // 147456 ushorts
  float* b1f  = F + 1320096;    // 448
  unsigned short* w1x  = (unsigned short*)(F + 1320544);  // 28672 ushorts
  unsigned short* w2x4 = (unsigned short*)(F + 1334880);  // 114688 ushorts

  float* out_main   = (float*)d_out;             // holds out1 between banks
  float* out_hidden = out_main + 16777216;
  float* out_logits = out_main + 16777280;

  // ---- attention bank ----
  k_zero   <<<64, 256, 0, stream>>>(M, 16384);
  k_statsxg<<<1024, 256, 0, stream>>>(x, mu1, rs1, ln1_w, ln1_b, part1, M);
  k_route  <<<1, 256, 0, stream>>>(part1, nullptr, ln1_w, ln1_b, hidden,
                                   ar1_w, ar1_b, ar3_w, ar3_b,
                                   h1a, l1, out_logits, 0, nullptr);
  k_expw   <<<12, 256, 0, stream>>>(M, att_qkv, att_temp, Weff);
  k_kmat   <<<36, 256, 0, stream>>>(Weff, att_dw, att_proj, l1, Ktb);
  k_conv   <<<1024, 256, 0, stream>>>(x, mu1, rs1, ln1_w, ln1_b, Ktb,
                                      beta, out_main, ln2_w, ln2_b,
                                      mu2, rs2, part2, smrp);
  // ---- MLP bank (out1 lives in d_out) ----
  k_route  <<<1, 256, 0, stream>>>(part2, smrp, ln2_w, ln2_b, h1a,
                                   mr1_w, mr1_b, mr3_w, mr3_b,
                                   h1m, l2, out_logits, 1, out_hidden);
  k_prep   <<<112, 256, 0, stream>>>(w1s[0], w1s[1], w1s[2], b1s[0], b1s[1], b1s[2],
                                     w2s[0], w2s[1], w2s[2], l2, w1x, w2x4, b1f);
  k_mlp    <<<2048, 256, 0, stream>>>(out_main, mu2, rs2, ln2_w, ln2_b,
                                      w1x, w2x4, b1f, b2s[0], b2s[1], b2s[2],
                                      gamma, l2);
}

// Round 20
// 246.853 us; speedup vs baseline: 1.0164x; 1.0014x over previous
//
#include <hip/hip_runtime.h>
#include <hip/hip_bf16.h>
#include <cstddef>

typedef __attribute__((ext_vector_type(8))) short short8;
typedef __attribute__((ext_vector_type(4))) float f32x4;

#define NPIX 65536  // 256*256

static __device__ __forceinline__ unsigned short f2bs(float f) {
  __hip_bfloat16 h = __float2bfloat16(f);
  return __builtin_bit_cast(unsigned short, h);
}
static __device__ __forceinline__ float s2f(short s) {
  union { unsigned u; float f; } v; v.u = ((unsigned)(unsigned short)s) << 16;
  return v.f;
}

__global__ void k_zero(float* __restrict__ p, int n) {
  int i = blockIdx.x * 256 + threadIdx.x;
  if (i < n) p[i] = 0.f;
}

// ---- fused bank-1 pre-pass: mu1/rs1 per pixel, xg1 partial sums (no atomics), Gram M ----
__global__ __launch_bounds__(256, 4)
void k_statsxg(const float* __restrict__ in, float* __restrict__ mu,
               float* __restrict__ rs, const float* __restrict__ lnw,
               const float* __restrict__ lnb, float* __restrict__ part1,
               float* __restrict__ M) {
  __shared__ __align__(16) short tile[64 * 264];   // [c][256 px + pad]
  int t = threadIdx.x;
  int pi = blockIdx.x * 256 + t;
  int b = blockIdx.x >> 8;
  const float* p = in + ((size_t)b << 22) + (pi & 65535);
  float s = 0.f, s2 = 0.f;
  #pragma unroll
  for (int c = 0; c < 64; ++c) {
    float v = p[(size_t)c << 16];
    s += v; s2 += v * v;
    tile[c * 264 + t] = (short)f2bs(v);
  }
  float m = s * 0.015625f;
  float var = s2 * 0.015625f - m * m;
  float rstd = rsqrtf(var + 1e-5f);
  mu[pi] = m; rs[pi] = rstd;
  #pragma unroll
  for (int c = 0; c < 64; ++c) {
    float lnv = (s2f(tile[c * 264 + t]) - m) * rstd * lnw[c] + lnb[c];
    tile[c * 264 + t] = (short)f2bs(lnv);          // own column only
  }
  __syncthreads();
  // per-channel row sums -> 4-lane combine -> ONE plain store per (block, channel)
  {
    int cB = t >> 2, qB = t & 3;
    float rsum = 0.f;
    #pragma unroll
    for (int i = 0; i < 8; ++i) {
      short8 vv = *(const short8*)(tile + cB * 264 + (qB << 6) + (i << 3));
      #pragma unroll
      for (int j = 0; j < 8; ++j) rsum += s2f(vv[j]);
    }
    rsum += __shfl_xor(rsum, 1, 64);
    rsum += __shfl_xor(rsum, 2, 64);
    if (qB == 0) part1[blockIdx.x * 64 + cB] = rsum;
  }
  // Gram: wave w computes rows 16w..16w+15 x all 64 cols, K = 256 px
  int l = t & 63, w = t >> 6, l15 = l & 15, g = l >> 4;
  f32x4 ga[4] = {{0,0,0,0},{0,0,0,0},{0,0,0,0},{0,0,0,0}};
  #pragma unroll
  for (int kt = 0; kt < 8; ++kt) {
    short8 af = *(const short8*)(tile + (16 * w + l15) * 264 + (kt << 5) + (g << 3));
    #pragma unroll
    for (int ot = 0; ot < 4; ++ot) {
      short8 bfg = *(const short8*)(tile + ((ot << 4) + l15) * 264 + (kt << 5) + (g << 3));
      ga[ot] = __builtin_amdgcn_mfma_f32_16x16x32_bf16(af, bfg, ga[ot], 0, 0, 0);
    }
  }
  float* Mb = M + b * 4096;
  #pragma unroll
  for (int ot = 0; ot < 4; ++ot)
    #pragma unroll
    for (int r = 0; r < 4; ++r)
      atomicAdd(&Mb[(16 * w + (g << 2) + r) * 64 + (ot << 4) + l15], ga[ot][r]);
}

// ---------------- routing (256 thr): reduce 256 partials/(b,c), then route ----------------
__global__ __launch_bounds__(256)
void k_route(const float* __restrict__ part, const float* __restrict__ smr_part,
             const float* __restrict__ lnw, const float* __restrict__ lnb,
             const float* __restrict__ hid,
             const float* __restrict__ w1, const float* __restrict__ b1,
             const float* __restrict__ w3, const float* __restrict__ b3,
             float* __restrict__ h1_out, float* __restrict__ logit_out,
             float* __restrict__ out_logits, int slot,
             float* __restrict__ out_hidden) {
  __shared__ float xgs[4][64];
  __shared__ float smrs[4];
  __shared__ float h1s[4][16];
  int t = threadIdx.x;                             // 256 threads
  {
    int bb = t >> 6, c = t & 63;
    const float* pp = part + (bb << 14) + c;
    float s = 0.f;
    for (int k = 0; k < 256; ++k) s += pp[k << 6];
    xgs[bb][c] = s;
  }
  if (smr_part && t < 4) {
    const float* sp = smr_part + (t << 8);
    float s = 0.f;
    for (int k = 0; k < 256; ++k) s += sp[k];
    smrs[t] = s;
  }
  __syncthreads();
  {
    int bb = t >> 6, c = t & 63;
    float v = xgs[bb][c];
    if (smr_part) v = (v - lnw[c] * smrs[bb]) * (1.f / 65536.f) + lnb[c];
    else          v = v * (1.f / 65536.f);
    xgs[bb][c] = v;
  }
  __syncthreads();
  if (t < 64) {
    int b = t >> 4, j = t & 15;
    float a = b1[j];
    for (int c = 0; c < 64; ++c) a += w1[j * 80 + c] * xgs[b][c];
    for (int k = 0; k < 16; ++k) a += w1[j * 80 + 64 + k] * hid[b * 16 + k];
    float g = 0.5f * a * (1.f + erff(a * 0.70710678f));   // exact gelu
    h1s[b][j] = g;
    h1_out[b * 16 + j] = g;
    if (out_hidden) out_hidden[b * 16 + j] = g;
  }
  __syncthreads();
  if (t < 12) {
    int b = t / 3, e = t % 3;
    float a = b3[e];
    for (int j = 0; j < 16; ++j) a += w3[e * 16 + j] * h1s[b][j];
    a = fmaxf(a, 0.f);
    logit_out[b * 3 + e] = a;
    out_logits[b * 6 + e * 2 + slot] = a;
  }
}

// ---------------- per (b,expert): softmax(q̂·k̂·temp) -> Weff = P @ Wv ----------------
__global__ void k_expw(const float* __restrict__ M, const float* __restrict__ qkv,
                       const float* __restrict__ temp, float* __restrict__ Weff) {
  int b = blockIdx.x / 3, e = blockIdx.x % 3;
  __shared__ float Ms[64][64];
  __shared__ float TQ[64][64];
  __shared__ float TK[64][64];
  __shared__ float P[64][4];
  __shared__ float nq[64], nk[64];
  const float* W = qkv + e * 12288;
  for (int idx = threadIdx.x; idx < 4096; idx += 256)
    Ms[idx >> 6][idx & 63] = M[b * 4096 + idx];
  __syncthreads();
  {
    int r = threadIdx.x >> 2;
    int v0 = (threadIdx.x & 3) << 4;
    float aq[16] = {}, ak[16] = {};
    for (int u = 0; u < 64; ++u) {
      float wq = W[r * 64 + u];
      float wk = W[(64 + r) * 64 + u];
      #pragma unroll
      for (int i = 0; i < 16; ++i) {
        float m = Ms[u][v0 + i];
        aq[i] += wq * m; ak[i] += wk * m;
      }
    }
    #pragma unroll
    for (int i = 0; i < 16; ++i) { TQ[r][v0 + i] = aq[i]; TK[r][v0 + i] = ak[i]; }
  }
  __syncthreads();
  if (threadIdx.x < 64) {
    int c = threadIdx.x;
    float sq = 0.f, sk = 0.f;
    for (int v = 0; v < 64; ++v) {
      sq += TQ[c][v] * W[c * 64 + v];
      sk += TK[c][v] * W[(64 + c) * 64 + v];
    }
    nq[c] = fmaxf(sqrtf(fmaxf(sq, 0.f)), 1e-12f);
    nk[c] = fmaxf(sqrtf(fmaxf(sk, 0.f)), 1e-12f);
  }
  __syncthreads();
  if (threadIdx.x < 64) {
    int rr = threadIdx.x, h = rr >> 2;
    float tp = temp[e * 16 + h];
    float s[4];
    #pragma unroll
    for (int d = 0; d < 4; ++d) {
      int kc = h * 4 + d;
      float g = 0.f;
      for (int v = 0; v < 64; ++v) g += TQ[rr][v] * W[(64 + kc) * 64 + v];
      s[d] = g / (nq[rr] * nk[kc]) * tp;
    }
    float mx = fmaxf(fmaxf(s[0], s[1]), fmaxf(s[2], s[3]));
    float es[4], sum = 0.f;
    #pragma unroll
    for (int d = 0; d < 4; ++d) { es[d] = __expf(s[d] - mx); sum += es[d]; }
    float inv = 1.f / sum;
    #pragma unroll
    for (int d = 0; d < 4; ++d) P[rr][d] = es[d] * inv;
  }
  __syncthreads();
  if (threadIdx.x < 64) {
    int rr = threadIdx.x, h = rr >> 2;
    for (int u = 0; u < 64; ++u) {
      float a = 0.f;
      #pragma unroll
      for (int d = 0; d < 4; ++d)
        a += P[rr][d] * W[(128 + h * 4 + d) * 64 + u];
      Weff[(size_t)(b * 3 + e) * 4096 + rr * 64 + u] = a;
    }
  }
}

// ------ Ktb[b][tap][o][u] = bf16( Σ_e l1_e Proj_e[o,c] dw_e[c,tap] Weff_e[c,u] ) ------
__global__ void k_kmat(const float* __restrict__ Weff, const float* __restrict__ dw,
                       const float* __restrict__ proj, const float* __restrict__ l1,
                       unsigned short* __restrict__ Ktb) {
  int b = blockIdx.x / 9, t = blockIdx.x % 9;
  __shared__ float S[64][68];
  __shared__ float Pr[64][68];
  int u = threadIdx.x >> 2, o0 = (threadIdx.x & 3) << 4;
  float acc[16] = {};
  for (int e = 0; e < 3; ++e) {
    __syncthreads();
    float le = l1[b * 3 + e];
    for (int idx = threadIdx.x; idx < 4096; idx += 256) {
      int c = idx >> 6, uu = idx & 63;
      S[c][uu] = le * dw[(e * 64 + c) * 9 + t] *
                 Weff[(size_t)(b * 3 + e) * 4096 + c * 64 + uu];
      Pr[c][uu] = proj[e * 4096 + uu * 64 + c];
    }
    __syncthreads();
    for (int c = 0; c < 64; ++c) {
      float sv = S[c][u];
      #pragma unroll
      for (int i = 0; i < 16; ++i) acc[i] += Pr[c][o0 + i] * sv;
    }
  }
  #pragma unroll
  for (int i = 0; i < 16; ++i)
    Ktb[(size_t)(b * 9 + t) * 4096 + (o0 + i) * 64 + u] = f2bs(acc[i]);
}

// -------- MFMA conv (channel-split halo, XCD-chunked swizzle) + residual
//          + fused LN2 stats/xg2 (no atomics) --------
__global__ __launch_bounds__(256, 4)
void k_conv(const float* __restrict__ x, const float* __restrict__ mu,
            const float* __restrict__ rs, const float* __restrict__ lw,
            const float* __restrict__ lb, const unsigned short* __restrict__ Ktb,
            const float* __restrict__ beta, float* __restrict__ out1,
            const float* __restrict__ lw2, const float* __restrict__ lb2,
            float* __restrict__ mu2, float* __restrict__ rs2,
            float* __restrict__ part2, float* __restrict__ smr_part) {
  __shared__ __align__(16) short lds[16896];
  __shared__ float rsL[256];
  __shared__ float wred[4];

  int tile = ((blockIdx.x & 7) << 7) + (blockIdx.x >> 3);  // bijective, 1024%8==0
  int bx = tile & 15, by = (tile >> 4) & 15, b = tile >> 8;
  int x0 = bx << 4, y0 = by << 4;
  int pb = tile;                                  // == (b<<8)|(by<<4)|bx
  int t = threadIdx.x;
  int w = t >> 6, l = t & 63, l15 = l & 15, g = l >> 4;

  int py = t >> 4, px = t & 15;
  int n_t = ((y0 + py) << 8) + x0 + px;
  int hpt = (py + 1) * 18 + (px + 1);
  float m1 = mu[(b << 16) + n_t], r1 = rs[(b << 16) + n_t];

  f32x4 acc[4][4] = {};
  const unsigned short* Kb = Ktb + (size_t)b * 36864;

  #pragma unroll 1
  for (int h = 0; h < 2; ++h) {
    int c0 = h << 5;
    #pragma unroll
    for (int cb = 0; cb < 4; ++cb) {
      short8 pk;
      #pragma unroll
      for (int i = 0; i < 8; ++i) {
        int c = c0 + (cb << 3) + i;
        float xv = x[((size_t)(b * 64 + c) << 16) + n_t];
        pk[i] = (short)f2bs((xv - m1) * r1 * lw[c] + lb[c]);
      }
      *(short8*)(lds + hpt * 32 + ((cb ^ (hpt & 3)) << 3)) = pk;
    }
    for (int idx = t; idx < 2176; idx += 256) {
      int bp = idx >> 5, cc = idx & 31;
      int hy, hx;
      if (bp < 18)      { hy = 0;  hx = bp; }
      else if (bp < 36) { hy = 17; hx = bp - 18; }
      else { int r2 = bp - 36; hy = 1 + (r2 >> 1); hx = (r2 & 1) ? 17 : 0; }
      int gy = y0 + hy - 1, gx = x0 + hx - 1;
      float v = 0.f;
      int c = c0 + cc;
      if ((unsigned)gy < 256u && (unsigned)gx < 256u) {
        int n = (gy << 8) + gx;
        v = (x[((size_t)(b * 64 + c) << 16) + n] - mu[(b << 16) + n]) *
            rs[(b << 16) + n] * lw[c] + lb[c];
      }
      int hp = hy * 18 + hx;
      lds[hp * 32 + (((cc >> 3) ^ (hp & 3)) << 3) + (cc & 7)] = (short)f2bs(v);
    }
    __syncthreads();
    int ky = 0, kx = 0;
    #pragma unroll 1
    for (int tap = 0; tap < 9; ++tap) {
      const unsigned short* Kt = Kb + (tap << 12);
      short8 bfr[4];
      #pragma unroll
      for (int ot = 0; ot < 4; ++ot)
        bfr[ot] = *(const short8*)(Kt + (((ot << 4) + l15) << 6) + c0 + (g << 3));
      #pragma unroll
      for (int mi = 0; mi < 4; ++mi) {
        int hp = ((w << 2) + mi + ky) * 18 + l15 + kx;
        short8 af = *(const short8*)(lds + hp * 32 + ((g ^ (hp & 3)) << 3));
        #pragma unroll
        for (int ot = 0; ot < 4; ++ot)
          acc[mi][ot] = __builtin_amdgcn_mfma_f32_16x16x32_bf16(af, bfr[ot], acc[mi][ot], 0, 0, 0);
      }
      if (++kx == 3) { kx = 0; ++ky; }
    }
    __syncthreads();
  }

  #pragma unroll
  for (int mi = 0; mi < 4; ++mi) {
    int p0 = (((w << 2) + mi) << 4) + (g << 2);
    #pragma unroll
    for (int ot = 0; ot < 4; ++ot) {
      int o = (ot << 4) + l15;
      short4 pk;
      pk.x = (short)f2bs(acc[mi][ot][0]);
      pk.y = (short)f2bs(acc[mi][ot][1]);
      pk.z = (short)f2bs(acc[mi][ot][2]);
      pk.w = (short)f2bs(acc[mi][ot][3]);
      *(short4*)(lds + o * 264 + p0) = pk;
    }
  }
  __syncthreads();

  // phase A: residual + store + LN2 stats (thread owns pixel t)
  float s = 0.f, s2 = 0.f;
  #pragma unroll
  for (int c = 0; c < 64; ++c) {
    size_t gi = ((size_t)(b * 64 + c) << 16) + n_t;
    float v = s2f(lds[c * 264 + t]) + beta[c] * x[gi];
    out1[gi] = v;
    s += v; s2 += v * v;
    lds[c * 264 + t] = (short)f2bs(v);           // own column only
  }
  float m = s * 0.015625f;
  float var = s2 * 0.015625f - m * m;
  float rstd = rsqrtf(var + 1e-5f);
  mu2[(b << 16) + n_t] = m;
  rs2[(b << 16) + n_t] = rstd;
  rsL[t] = rstd;
  float mr = m * rstd;
  #pragma unroll
  for (int o = 32; o > 0; o >>= 1) mr += __shfl_down(mr, o, 64);
  if (l == 0) wred[w] = mr;
  __syncthreads();
  if (t == 0) smr_part[pb] = wred[0] + wred[1] + wred[2] + wred[3];

  // phase B: per-channel Σ v·rstd -> 4-lane combine -> ONE plain store
  int cB = t >> 2, qB = t & 3;
  float sv = 0.f;
  #pragma unroll
  for (int i = 0; i < 8; ++i) {
    short8 vv = *(const short8*)(lds + cB * 264 + (qB << 6) + (i << 3));
    #pragma unroll
    for (int j = 0; j < 8; ++j) sv += s2f(vv[j]) * rsL[(qB << 6) + (i << 3) + j];
  }
  sv += __shfl_xor(sv, 1, 64);
  sv += __shfl_xor(sv, 2, 64);
  if (qB == 0) part2[pb * 64 + cB] = sv * lw2[cB];
}

// ------ prep MLP weights PRE-SWIZZLED to per-lane load order ------
__global__ void k_prep(const float* __restrict__ w1_0, const float* __restrict__ w1_1,
                       const float* __restrict__ w1_2,
                       const float* __restrict__ b1_0, const float* __restrict__ b1_1,
                       const float* __restrict__ b1_2,
                       const float* __restrict__ w2_0, const float* __restrict__ w2_1,
                       const float* __restrict__ w2_2,
                       const float* __restrict__ l2,
                       unsigned short* __restrict__ w1x, unsigned short* __restrict__ w2x4,
                       float* __restrict__ b1f) {
  int idx = blockIdx.x * 256 + threadIdx.x;
  if (idx >= 28672) return;
  int instr = idx >> 9, r = idx & 511;
  int li = r >> 3, i = r & 7;
  int l15 = li & 15, g = li >> 4;
  // ---- w1x ----
  {
    int jb = instr >> 2, q = (instr >> 1) & 1, ks = instr & 1;
    int jt = jb * 32 + ((l15 >> 2) << 3) + (l15 & 3) + (q << 2);
    int c = (ks << 5) + (g << 3) + i;
    int e, j;
    if (jt < 64)       { e = 0; j = jt; }
    else if (jt < 192) { e = 1; j = jt - 64; }
    else               { e = 2; j = jt - 192; }
    const float* w1 = e == 0 ? w1_0 : (e == 1 ? w1_1 : w1_2);
    w1x[idx] = f2bs(w1[j * 64 + c]);
  }
  // ---- w2x4 (4 batches, l2 pre-scaled) ----
  {
    int jb = instr >> 2, ot = instr & 3;
    int o = (ot << 4) + l15;
    int j = jb * 32 + (g << 3) + i;
    int e, jj;
    if (j < 64)       { e = 0; jj = j; }
    else if (j < 192) { e = 1; jj = j - 64; }
    else              { e = 2; jj = j - 192; }
    const float* w2 = e == 0 ? w2_0 : (e == 1 ? w2_1 : w2_2);
    int hf = 64 << e;
    float v = w2[o * hf + jj];
    #pragma unroll
    for (int bb = 0; bb < 4; ++bb)
      w2x4[bb * 28672 + idx] = f2bs(v * l2[bb * 3 + e]);
  }
  // ---- b1f ----
  if (idx < 448) {
    int jt = idx, e, j;
    if (jt < 64)       { e = 0; j = jt; }
    else if (jt < 192) { e = 1; j = jt - 64; }
    else               { e = 2; j = jt - 192; }
    const float* b1 = e == 0 ? b1_0 : (e == 1 ? b1_1 : b1_2);
    b1f[jt] = b1[j];
  }
}

// ---------------- MFMA fused MLP bank, LDS-free, raw-intrinsic gelu ----------------
__global__ __launch_bounds__(256, 3)
void k_mlp(float* io,
           const float* __restrict__ mu2, const float* __restrict__ rs2,
           const float* __restrict__ lw, const float* __restrict__ lb,
           const unsigned short* __restrict__ w1x, const unsigned short* __restrict__ w2x4,
           const float* __restrict__ b1f,
           const float* __restrict__ b2_0, const float* __restrict__ b2_1,
           const float* __restrict__ b2_2,
           const float* __restrict__ gamma, const float* __restrict__ l2) {
  int b  = blockIdx.x >> 9;
  int n0 = (blockIdx.x & 511) << 7;
  int t  = threadIdx.x;
  int w  = t >> 6, l = t & 63;
  int l15 = l & 15, g = l >> 4;

  size_t iob = ((size_t)b << 22) + n0;
  float l2v0 = l2[b * 3], l2v1 = l2[b * 3 + 1], l2v2 = l2[b * 3 + 2];
  const unsigned short* w2b = w2x4 + b * 28672;

  short8 xf[2][2];
  #pragma unroll
  for (int pf = 0; pf < 2; ++pf) {
    int pl = (w << 5) + (pf << 4) + l15;
    float muv = mu2[(b << 16) + n0 + pl];
    float rsv = rs2[(b << 16) + n0 + pl];
    #pragma unroll
    for (int ks = 0; ks < 2; ++ks)
      #pragma unroll
      for (int i = 0; i < 8; ++i) {
        int c = (ks << 5) + (g << 3) + i;
        float v = (io[iob + ((size_t)c << 16) + pl] - muv) * rsv * lw[c] + lb[c];
        xf[pf][ks][i] = (short)f2bs(v);
      }
  }

  f32x4 acc2[2][4] = {{{0,0,0,0},{0,0,0,0},{0,0,0,0},{0,0,0,0}},
                      {{0,0,0,0},{0,0,0,0},{0,0,0,0},{0,0,0,0}}};

  const float GA = -2.3022081f;   // -2*log2(e)*0.7978845608
  const float GB = -0.1029437f;   // -2*log2(e)*0.0356774081

  #pragma unroll 2
  for (int jb = 0; jb < 14; ++jb) {
    int j0 = jb << 5;
    short8 w1a[2][2];
    f32x4 b1v[2];
    #pragma unroll
    for (int q = 0; q < 2; ++q) {
      int ibase = ((jb << 1) | q) << 1;
      w1a[q][0] = *(const short8*)(w1x + ((ibase | 0) << 9) + (l << 3));
      w1a[q][1] = *(const short8*)(w1x + ((ibase | 1) << 9) + (l << 3));
      b1v[q] = *(const f32x4*)(b1f + j0 + (g << 3) + (q << 2));
    }
    short8 A2[2];
    #pragma unroll
    for (int pf = 0; pf < 2; ++pf) {
      #pragma unroll
      for (int q = 0; q < 2; ++q) {
        f32x4 d1 = {0.f, 0.f, 0.f, 0.f};
        d1 = __builtin_amdgcn_mfma_f32_16x16x32_bf16(w1a[q][0], xf[pf][0], d1, 0, 0, 0);
        d1 = __builtin_amdgcn_mfma_f32_16x16x32_bf16(w1a[q][1], xf[pf][1], d1, 0, 0, 0);
        #pragma unroll
        for (int r = 0; r < 4; ++r) {
          float tv = d1[r] + b1v[q][r];
          float t2 = tv * tv;
          float arg = tv * (GA + GB * t2);
          float e1 = __builtin_amdgcn_exp2f(arg);           // raw v_exp_f32
          float gv = tv * __builtin_amdgcn_rcpf(1.f + e1);  // raw v_rcp_f32
          A2[pf][(q << 2) + r] = (short)f2bs(gv);
        }
      }
    }
    #pragma unroll
    for (int ot = 0; ot < 4; ++ot) {
      short8 w2f = *(const short8*)(w2b + (((jb << 2) | ot) << 9) + (l << 3));
      acc2[0][ot] = __builtin_amdgcn_mfma_f32_16x16x32_bf16(A2[0], w2f, acc2[0][ot], 0, 0, 0);
      acc2[1][ot] = __builtin_amdgcn_mfma_f32_16x16x32_bf16(A2[1], w2f, acc2[1][ot], 0, 0, 0);
    }
  }

  #pragma unroll
  for (int ot = 0; ot < 4; ++ot) {
    int o = (ot << 4) + l15;
    float bias = l2v0 * b2_0[o] + l2v1 * b2_1[o] + l2v2 * b2_2[o];
    float gmv = gamma[o];
    #pragma unroll
    for (int pf = 0; pf < 2; ++pf) {
      int p0 = (w << 5) + (pf << 4) + (g << 2);
      float* gp = io + iob + ((size_t)o << 16) + p0;
      f32x4 old = *(const f32x4*)gp;
      f32x4 res;
      #pragma unroll
      for (int r = 0; r < 4; ++r)
        res[r] = acc2[pf][ot][r] + gmv * old[r] + bias;
      *(f32x4*)gp = res;
    }
  }
}

extern "C" void kernel_launch(void* const* d_in, const int* in_sizes, int n_in,
                              void* d_out, int out_size, void* d_ws, size_t ws_size,
                              hipStream_t stream) {
  (void)in_sizes; (void)n_in; (void)out_size; (void)ws_size;
  const float* x        = (const float*)d_in[0];
  const float* hidden   = (const float*)d_in[1];
  const float* ln1_w    = (const float*)d_in[2];
  const float* ln1_b    = (const float*)d_in[3];
  const float* ln2_w    = (const float*)d_in[4];
  const float* ln2_b    = (const float*)d_in[5];
  const float* beta     = (const float*)d_in[6];
  const float* gamma    = (const float*)d_in[7];
  const float* att_temp = (const float*)d_in[8];
  const float* att_qkv  = (const float*)d_in[9];
  const float* att_dw   = (const float*)d_in[10];
  const float* att_proj = (const float*)d_in[11];
  const float* ar1_w    = (const float*)d_in[12];
  const float* ar1_b    = (const float*)d_in[13];
  const float* ar3_w    = (const float*)d_in[14];
  const float* ar3_b    = (const float*)d_in[15];
  const float* mr1_w    = (const float*)d_in[16];
  const float* mr1_b    = (const float*)d_in[17];
  const float* mr3_w    = (const float*)d_in[18];
  const float* mr3_b    = (const float*)d_in[19];
  const float* w1s[3] = {(const float*)d_in[20], (const float*)d_in[24], (const float*)d_in[28]};
  const float* b1s[3] = {(const float*)d_in[21], (const float*)d_in[25], (const float*)d_in[29]};
  const float* w2s[3] = {(const float*)d_in[22], (const float*)d_in[26], (const float*)d_in[30]};
  const float* b2s[3] = {(const float*)d_in[23], (const float*)d_in[27], (const float*)d_in[31]};

  // ---- workspace (~5.6 MB fp32) ----
  float* F    = (float*)d_ws;
  float* mu1  = F + 0;          // 262144
  float* rs1  = F + 262144;     // 262144
  float* mu2  = F + 524288;     // 262144
  float* rs2  = F + 786432;     // 262144
  float* M    = F + 1048576;    // 16384  (zeroed)
  float* part1= F + 1064960;    // 65536
  float* part2= F + 1130496;    // 65536
  float* smrp = F + 1196032;    // 1024
  float* h1a  = F + 1197056;    // 64
  float* h1m  = F + 1197120;    // 64
  float* l1   = F + 1197184;    // 16
  float* l2   = F + 1197200;    // 16
  float* Weff = F + 1197216;    // 49152
  unsigned short* Ktb = (unsigned short*)(F + 1246368);   // 147456 ushorts
  float* b1f  = F + 1320096;    // 448
  unsigned short* w1x  = (unsigned short*)(F + 1320544);  // 28672 ushorts
  unsigned short* w2x4 = (unsigned short*)(F + 1334880);  // 114688 ushorts

  float* out_main   = (float*)d_out;             // holds out1 between banks
  float* out_hidden = out_main + 16777216;
  float* out_logits = out_main + 16777280;

  // ---- attention bank ----
  k_zero   <<<64, 256, 0, stream>>>(M, 16384);
  k_statsxg<<<1024, 256, 0, stream>>>(x, mu1, rs1, ln1_w, ln1_b, part1, M);
  k_route  <<<1, 256, 0, stream>>>(part1, nullptr, ln1_w, ln1_b, hidden,
                                   ar1_w, ar1_b, ar3_w, ar3_b,
                                   h1a, l1, out_logits, 0, nullptr);
  k_expw   <<<12, 256, 0, stream>>>(M, att_qkv, att_temp, Weff);
  k_kmat   <<<36, 256, 0, stream>>>(Weff, att_dw, att_proj, l1, Ktb);
  k_conv   <<<1024, 256, 0, stream>>>(x, mu1, rs1, ln1_w, ln1_b, Ktb,
                                      beta, out_main, ln2_w, ln2_b,
                                      mu2, rs2, part2, smrp);
  // ---- MLP bank (out1 lives in d_out) ----
  k_route  <<<1, 256, 0, stream>>>(part2, smrp, ln2_w, ln2_b, h1a,
                                   mr1_w, mr1_b, mr3_w, mr3_b,
                                   h1m, l2, out_logits, 1, out_hidden);
  k_prep   <<<112, 256, 0, stream>>>(w1s[0], w1s[1], w1s[2], b1s[0], b1s[1], b1s[2],
                                     w2s[0], w2s[1], w2s[2], l2, w1x, w2x4, b1f);
  k_mlp    <<<2048, 256, 0, stream>>>(out_main, mu2, rs2, ln2_w, ln2_b,
                                      w1x, w2x4, b1f, b2s[0], b2s[1], b2s[2],
                                      gamma, l2);
}

// Round 21
// 244.514 us; speedup vs baseline: 1.0262x; 1.0096x over previous
//
#include <hip/hip_runtime.h>
#include <hip/hip_bf16.h>
#include <cstddef>

typedef __attribute__((ext_vector_type(8))) short short8;
typedef __attribute__((ext_vector_type(4))) float f32x4;

#define NPIX 65536  // 256*256

static __device__ __forceinline__ unsigned short f2bs(float f) {
  __hip_bfloat16 h = __float2bfloat16(f);
  return __builtin_bit_cast(unsigned short, h);
}
static __device__ __forceinline__ float s2f(short s) {
  union { unsigned u; float f; } v; v.u = ((unsigned)(unsigned short)s) << 16;
  return v.f;
}

__global__ void k_zero(float* __restrict__ p, int n) {
  int i = blockIdx.x * 256 + threadIdx.x;
  if (i < n) p[i] = 0.f;
}

// ---- fused bank-1 pre-pass: mu/rs (packed float2) per pixel, xg1 partials, Gram M ----
__global__ __launch_bounds__(256, 4)
void k_statsxg(const float* __restrict__ in, float* __restrict__ mr,
               const float* __restrict__ lnw, const float* __restrict__ lnb,
               float* __restrict__ part1, float* __restrict__ M) {
  __shared__ __align__(16) short tile[64 * 264];   // [c][256 px + pad]
  int t = threadIdx.x;
  int pi = blockIdx.x * 256 + t;
  int b = blockIdx.x >> 8;
  const float* p = in + ((size_t)b << 22) + (pi & 65535);
  float s = 0.f, s2 = 0.f;
  #pragma unroll
  for (int c = 0; c < 64; ++c) {
    float v = p[(size_t)c << 16];
    s += v; s2 += v * v;
    tile[c * 264 + t] = (short)f2bs(v);
  }
  float m = s * 0.015625f;
  float var = s2 * 0.015625f - m * m;
  float rstd = rsqrtf(var + 1e-5f);
  *(float2*)(mr + 2 * (size_t)pi) = make_float2(m, rstd);
  #pragma unroll
  for (int c = 0; c < 64; ++c) {
    float lnv = (s2f(tile[c * 264 + t]) - m) * rstd * lnw[c] + lnb[c];
    tile[c * 264 + t] = (short)f2bs(lnv);          // own column only
  }
  __syncthreads();
  // per-channel row sums -> 4-lane combine -> ONE plain store per (block, channel)
  {
    int cB = t >> 2, qB = t & 3;
    float rsum = 0.f;
    #pragma unroll
    for (int i = 0; i < 8; ++i) {
      short8 vv = *(const short8*)(tile + cB * 264 + (qB << 6) + (i << 3));
      #pragma unroll
      for (int j = 0; j < 8; ++j) rsum += s2f(vv[j]);
    }
    rsum += __shfl_xor(rsum, 1, 64);
    rsum += __shfl_xor(rsum, 2, 64);
    if (qB == 0) part1[blockIdx.x * 64 + cB] = rsum;
  }
  // Gram: wave w computes rows 16w..16w+15 x all 64 cols, K = 256 px
  int l = t & 63, w = t >> 6, l15 = l & 15, g = l >> 4;
  f32x4 ga[4] = {{0,0,0,0},{0,0,0,0},{0,0,0,0},{0,0,0,0}};
  #pragma unroll
  for (int kt = 0; kt < 8; ++kt) {
    short8 af = *(const short8*)(tile + (16 * w + l15) * 264 + (kt << 5) + (g << 3));
    #pragma unroll
    for (int ot = 0; ot < 4; ++ot) {
      short8 bfg = *(const short8*)(tile + ((ot << 4) + l15) * 264 + (kt << 5) + (g << 3));
      ga[ot] = __builtin_amdgcn_mfma_f32_16x16x32_bf16(af, bfg, ga[ot], 0, 0, 0);
    }
  }
  float* Mb = M + b * 4096;
  #pragma unroll
  for (int ot = 0; ot < 4; ++ot)
    #pragma unroll
    for (int r = 0; r < 4; ++r)
      atomicAdd(&Mb[(16 * w + (g << 2) + r) * 64 + (ot << 4) + l15], ga[ot][r]);
}

// ---------------- routing (256 thr): reduce 256 partials/(b,c), then route ----------------
__global__ __launch_bounds__(256)
void k_route(const float* __restrict__ part, const float* __restrict__ smr_part,
             const float* __restrict__ lnw, const float* __restrict__ lnb,
             const float* __restrict__ hid,
             const float* __restrict__ w1, const float* __restrict__ b1,
             const float* __restrict__ w3, const float* __restrict__ b3,
             float* __restrict__ h1_out, float* __restrict__ logit_out,
             float* __restrict__ out_logits, int slot,
             float* __restrict__ out_hidden) {
  __shared__ float xgs[4][64];
  __shared__ float smrs[4];
  __shared__ float h1s[4][16];
  int t = threadIdx.x;                             // 256 threads
  {
    int bb = t >> 6, c = t & 63;
    const float* pp = part + (bb << 14) + c;
    float s = 0.f;
    for (int k = 0; k < 256; ++k) s += pp[k << 6];
    xgs[bb][c] = s;
  }
  if (smr_part && t < 4) {
    const float* sp = smr_part + (t << 8);
    float s = 0.f;
    for (int k = 0; k < 256; ++k) s += sp[k];
    smrs[t] = s;
  }
  __syncthreads();
  {
    int bb = t >> 6, c = t & 63;
    float v = xgs[bb][c];
    if (smr_part) v = (v - lnw[c] * smrs[bb]) * (1.f / 65536.f) + lnb[c];
    else          v = v * (1.f / 65536.f);
    xgs[bb][c] = v;
  }
  __syncthreads();
  if (t < 64) {
    int b = t >> 4, j = t & 15;
    float a = b1[j];
    for (int c = 0; c < 64; ++c) a += w1[j * 80 + c] * xgs[b][c];
    for (int k = 0; k < 16; ++k) a += w1[j * 80 + 64 + k] * hid[b * 16 + k];
    float g = 0.5f * a * (1.f + erff(a * 0.70710678f));   // exact gelu
    h1s[b][j] = g;
    h1_out[b * 16 + j] = g;
    if (out_hidden) out_hidden[b * 16 + j] = g;
  }
  __syncthreads();
  if (t < 12) {
    int b = t / 3, e = t % 3;
    float a = b3[e];
    for (int j = 0; j < 16; ++j) a += w3[e * 16 + j] * h1s[b][j];
    a = fmaxf(a, 0.f);
    logit_out[b * 3 + e] = a;
    out_logits[b * 6 + e * 2 + slot] = a;
  }
}

// ---------------- per (b,expert): softmax(q̂·k̂·temp) -> Weff = P @ Wv ----------------
__global__ void k_expw(const float* __restrict__ M, const float* __restrict__ qkv,
                       const float* __restrict__ temp, float* __restrict__ Weff) {
  int b = blockIdx.x / 3, e = blockIdx.x % 3;
  __shared__ float Ms[64][64];
  __shared__ float TQ[64][64];
  __shared__ float TK[64][64];
  __shared__ float P[64][4];
  __shared__ float nq[64], nk[64];
  const float* W = qkv + e * 12288;
  for (int idx = threadIdx.x; idx < 4096; idx += 256)
    Ms[idx >> 6][idx & 63] = M[b * 4096 + idx];
  __syncthreads();
  {
    int r = threadIdx.x >> 2;
    int v0 = (threadIdx.x & 3) << 4;
    float aq[16] = {}, ak[16] = {};
    for (int u = 0; u < 64; ++u) {
      float wq = W[r * 64 + u];
      float wk = W[(64 + r) * 64 + u];
      #pragma unroll
      for (int i = 0; i < 16; ++i) {
        float m = Ms[u][v0 + i];
        aq[i] += wq * m; ak[i] += wk * m;
      }
    }
    #pragma unroll
    for (int i = 0; i < 16; ++i) { TQ[r][v0 + i] = aq[i]; TK[r][v0 + i] = ak[i]; }
  }
  __syncthreads();
  if (threadIdx.x < 64) {
    int c = threadIdx.x;
    float sq = 0.f, sk = 0.f;
    for (int v = 0; v < 64; ++v) {
      sq += TQ[c][v] * W[c * 64 + v];
      sk += TK[c][v] * W[(64 + c) * 64 + v];
    }
    nq[c] = fmaxf(sqrtf(fmaxf(sq, 0.f)), 1e-12f);
    nk[c] = fmaxf(sqrtf(fmaxf(sk, 0.f)), 1e-12f);
  }
  __syncthreads();
  if (threadIdx.x < 64) {
    int rr = threadIdx.x, h = rr >> 2;
    float tp = temp[e * 16 + h];
    float s[4];
    #pragma unroll
    for (int d = 0; d < 4; ++d) {
      int kc = h * 4 + d;
      float g = 0.f;
      for (int v = 0; v < 64; ++v) g += TQ[rr][v] * W[(64 + kc) * 64 + v];
      s[d] = g / (nq[rr] * nk[kc]) * tp;
    }
    float mx = fmaxf(fmaxf(s[0], s[1]), fmaxf(s[2], s[3]));
    float es[4], sum = 0.f;
    #pragma unroll
    for (int d = 0; d < 4; ++d) { es[d] = __expf(s[d] - mx); sum += es[d]; }
    float inv = 1.f / sum;
    #pragma unroll
    for (int d = 0; d < 4; ++d) P[rr][d] = es[d] * inv;
  }
  __syncthreads();
  if (threadIdx.x < 64) {
    int rr = threadIdx.x, h = rr >> 2;
    for (int u = 0; u < 64; ++u) {
      float a = 0.f;
      #pragma unroll
      for (int d = 0; d < 4; ++d)
        a += P[rr][d] * W[(128 + h * 4 + d) * 64 + u];
      Weff[(size_t)(b * 3 + e) * 4096 + rr * 64 + u] = a;
    }
  }
}

// ------ Ktb[b][tap][o][u] = bf16( Σ_e l1_e Proj_e[o,c] dw_e[c,tap] Weff_e[c,u] ) ------
__global__ void k_kmat(const float* __restrict__ Weff, const float* __restrict__ dw,
                       const float* __restrict__ proj, const float* __restrict__ l1,
                       unsigned short* __restrict__ Ktb) {
  int b = blockIdx.x / 9, t = blockIdx.x % 9;
  __shared__ float S[64][68];
  __shared__ float Pr[64][68];
  int u = threadIdx.x >> 2, o0 = (threadIdx.x & 3) << 4;
  float acc[16] = {};
  for (int e = 0; e < 3; ++e) {
    __syncthreads();
    float le = l1[b * 3 + e];
    for (int idx = threadIdx.x; idx < 4096; idx += 256) {
      int c = idx >> 6, uu = idx & 63;
      S[c][uu] = le * dw[(e * 64 + c) * 9 + t] *
                 Weff[(size_t)(b * 3 + e) * 4096 + c * 64 + uu];
      Pr[c][uu] = proj[e * 4096 + uu * 64 + c];
    }
    __syncthreads();
    for (int c = 0; c < 64; ++c) {
      float sv = S[c][u];
      #pragma unroll
      for (int i = 0; i < 16; ++i) acc[i] += Pr[c][o0 + i] * sv;
    }
  }
  #pragma unroll
  for (int i = 0; i < 16; ++i)
    Ktb[(size_t)(b * 9 + t) * 4096 + (o0 + i) * 64 + u] = f2bs(acc[i]);
}

// -------- MFMA conv (channel-split halo, XCD-chunked swizzle) + residual
//          + fused LN2 stats/xg2 (no atomics); mu/rs packed float2 --------
__global__ __launch_bounds__(256, 4)
void k_conv(const float* __restrict__ x, const float* __restrict__ mr1,
            const float* __restrict__ lw, const float* __restrict__ lb,
            const unsigned short* __restrict__ Ktb,
            const float* __restrict__ beta, float* __restrict__ out1,
            const float* __restrict__ lw2, const float* __restrict__ lb2,
            float* __restrict__ mr2,
            float* __restrict__ part2, float* __restrict__ smr_part) {
  __shared__ __align__(16) short lds[16896];
  __shared__ float rsL[256];
  __shared__ float wred[4];

  int tile = ((blockIdx.x & 7) << 7) + (blockIdx.x >> 3);  // bijective, 1024%8==0
  int bx = tile & 15, by = (tile >> 4) & 15, b = tile >> 8;
  int x0 = bx << 4, y0 = by << 4;
  int pb = tile;                                  // == (b<<8)|(by<<4)|bx
  int t = threadIdx.x;
  int w = t >> 6, l = t & 63, l15 = l & 15, g = l >> 4;

  int py = t >> 4, px = t & 15;
  int n_t = ((y0 + py) << 8) + x0 + px;
  int hpt = (py + 1) * 18 + (px + 1);
  float2 mr_t = *(const float2*)(mr1 + 2 * (size_t)((b << 16) + n_t));
  float m1 = mr_t.x, r1 = mr_t.y;

  f32x4 acc[4][4] = {};
  const unsigned short* Kb = Ktb + (size_t)b * 36864;

  #pragma unroll 1
  for (int h = 0; h < 2; ++h) {
    int c0 = h << 5;
    #pragma unroll
    for (int cb = 0; cb < 4; ++cb) {
      short8 pk;
      #pragma unroll
      for (int i = 0; i < 8; ++i) {
        int c = c0 + (cb << 3) + i;
        float xv = x[((size_t)(b * 64 + c) << 16) + n_t];
        pk[i] = (short)f2bs((xv - m1) * r1 * lw[c] + lb[c]);
      }
      *(short8*)(lds + hpt * 32 + ((cb ^ (hpt & 3)) << 3)) = pk;
    }
    for (int idx = t; idx < 2176; idx += 256) {
      int bp = idx >> 5, cc = idx & 31;
      int hy, hx;
      if (bp < 18)      { hy = 0;  hx = bp; }
      else if (bp < 36) { hy = 17; hx = bp - 18; }
      else { int r2 = bp - 36; hy = 1 + (r2 >> 1); hx = (r2 & 1) ? 17 : 0; }
      int gy = y0 + hy - 1, gx = x0 + hx - 1;
      float v = 0.f;
      int c = c0 + cc;
      if ((unsigned)gy < 256u && (unsigned)gx < 256u) {
        int n = (gy << 8) + gx;
        float2 mrv = *(const float2*)(mr1 + 2 * (size_t)((b << 16) + n));
        v = (x[((size_t)(b * 64 + c) << 16) + n] - mrv.x) * mrv.y * lw[c] + lb[c];
      }
      int hp = hy * 18 + hx;
      lds[hp * 32 + (((cc >> 3) ^ (hp & 3)) << 3) + (cc & 7)] = (short)f2bs(v);
    }
    __syncthreads();
    int ky = 0, kx = 0;
    #pragma unroll 1
    for (int tap = 0; tap < 9; ++tap) {
      const unsigned short* Kt = Kb + (tap << 12);
      short8 bfr[4];
      #pragma unroll
      for (int ot = 0; ot < 4; ++ot)
        bfr[ot] = *(const short8*)(Kt + (((ot << 4) + l15) << 6) + c0 + (g << 3));
      #pragma unroll
      for (int mi = 0; mi < 4; ++mi) {
        int hp = ((w << 2) + mi + ky) * 18 + l15 + kx;
        short8 af = *(const short8*)(lds + hp * 32 + ((g ^ (hp & 3)) << 3));
        #pragma unroll
        for (int ot = 0; ot < 4; ++ot)
          acc[mi][ot] = __builtin_amdgcn_mfma_f32_16x16x32_bf16(af, bfr[ot], acc[mi][ot], 0, 0, 0);
      }
      if (++kx == 3) { kx = 0; ++ky; }
    }
    __syncthreads();
  }

  #pragma unroll
  for (int mi = 0; mi < 4; ++mi) {
    int p0 = (((w << 2) + mi) << 4) + (g << 2);
    #pragma unroll
    for (int ot = 0; ot < 4; ++ot) {
      int o = (ot << 4) + l15;
      short4 pk;
      pk.x = (short)f2bs(acc[mi][ot][0]);
      pk.y = (short)f2bs(acc[mi][ot][1]);
      pk.z = (short)f2bs(acc[mi][ot][2]);
      pk.w = (short)f2bs(acc[mi][ot][3]);
      *(short4*)(lds + o * 264 + p0) = pk;
    }
  }
  __syncthreads();

  // phase A: residual + store + LN2 stats (thread owns pixel t)
  float s = 0.f, s2 = 0.f;
  #pragma unroll
  for (int c = 0; c < 64; ++c) {
    size_t gi = ((size_t)(b * 64 + c) << 16) + n_t;
    float v = s2f(lds[c * 264 + t]) + beta[c] * x[gi];
    out1[gi] = v;
    s += v; s2 += v * v;
    lds[c * 264 + t] = (short)f2bs(v);           // own column only
  }
  float m = s * 0.015625f;
  float var = s2 * 0.015625f - m * m;
  float rstd = rsqrtf(var + 1e-5f);
  *(float2*)(mr2 + 2 * (size_t)((b << 16) + n_t)) = make_float2(m, rstd);
  rsL[t] = rstd;
  float mr = m * rstd;
  #pragma unroll
  for (int o = 32; o > 0; o >>= 1) mr += __shfl_down(mr, o, 64);
  if (l == 0) wred[w] = mr;
  __syncthreads();
  if (t == 0) smr_part[pb] = wred[0] + wred[1] + wred[2] + wred[3];

  // phase B: per-channel Σ v·rstd -> 4-lane combine -> ONE plain store
  int cB = t >> 2, qB = t & 3;
  float sv = 0.f;
  #pragma unroll
  for (int i = 0; i < 8; ++i) {
    short8 vv = *(const short8*)(lds + cB * 264 + (qB << 6) + (i << 3));
    #pragma unroll
    for (int j = 0; j < 8; ++j) sv += s2f(vv[j]) * rsL[(qB << 6) + (i << 3) + j];
  }
  sv += __shfl_xor(sv, 1, 64);
  sv += __shfl_xor(sv, 2, 64);
  if (qB == 0) part2[pb * 64 + cB] = sv * lw2[cB];
}

// ------ prep MLP weights PRE-SWIZZLED to per-lane load order ------
__global__ void k_prep(const float* __restrict__ w1_0, const float* __restrict__ w1_1,
                       const float* __restrict__ w1_2,
                       const float* __restrict__ b1_0, const float* __restrict__ b1_1,
                       const float* __restrict__ b1_2,
                       const float* __restrict__ w2_0, const float* __restrict__ w2_1,
                       const float* __restrict__ w2_2,
                       const float* __restrict__ l2,
                       unsigned short* __restrict__ w1x, unsigned short* __restrict__ w2x4,
                       float* __restrict__ b1f) {
  int idx = blockIdx.x * 256 + threadIdx.x;
  if (idx >= 28672) return;
  int instr = idx >> 9, r = idx & 511;
  int li = r >> 3, i = r & 7;
  int l15 = li & 15, g = li >> 4;
  // ---- w1x ----
  {
    int jb = instr >> 2, q = (instr >> 1) & 1, ks = instr & 1;
    int jt = jb * 32 + ((l15 >> 2) << 3) + (l15 & 3) + (q << 2);
    int c = (ks << 5) + (g << 3) + i;
    int e, j;
    if (jt < 64)       { e = 0; j = jt; }
    else if (jt < 192) { e = 1; j = jt - 64; }
    else               { e = 2; j = jt - 192; }
    const float* w1 = e == 0 ? w1_0 : (e == 1 ? w1_1 : w1_2);
    w1x[idx] = f2bs(w1[j * 64 + c]);
  }
  // ---- w2x4 (4 batches, l2 pre-scaled) ----
  {
    int jb = instr >> 2, ot = instr & 3;
    int o = (ot << 4) + l15;
    int j = jb * 32 + (g << 3) + i;
    int e, jj;
    if (j < 64)       { e = 0; jj = j; }
    else if (j < 192) { e = 1; jj = j - 64; }
    else              { e = 2; jj = j - 192; }
    const float* w2 = e == 0 ? w2_0 : (e == 1 ? w2_1 : w2_2);
    int hf = 64 << e;
    float v = w2[o * hf + jj];
    #pragma unroll
    for (int bb = 0; bb < 4; ++bb)
      w2x4[bb * 28672 + idx] = f2bs(v * l2[bb * 3 + e]);
  }
  // ---- b1f ----
  if (idx < 448) {
    int jt = idx, e, j;
    if (jt < 64)       { e = 0; j = jt; }
    else if (jt < 192) { e = 1; j = jt - 64; }
    else               { e = 2; j = jt - 192; }
    const float* b1 = e == 0 ? b1_0 : (e == 1 ? b1_1 : b1_2);
    b1f[jt] = b1[j];
  }
}

// ---------------- MFMA fused MLP bank, LDS-free, raw-intrinsic gelu ----------------
__global__ __launch_bounds__(256, 3)
void k_mlp(float* io,
           const float* __restrict__ mr2,
           const float* __restrict__ lw, const float* __restrict__ lb,
           const unsigned short* __restrict__ w1x, const unsigned short* __restrict__ w2x4,
           const float* __restrict__ b1f,
           const float* __restrict__ b2_0, const float* __restrict__ b2_1,
           const float* __restrict__ b2_2,
           const float* __restrict__ gamma, const float* __restrict__ l2) {
  int b  = blockIdx.x >> 9;
  int n0 = (blockIdx.x & 511) << 7;
  int t  = threadIdx.x;
  int w  = t >> 6, l = t & 63;
  int l15 = l & 15, g = l >> 4;

  size_t iob = ((size_t)b << 22) + n0;
  float l2v0 = l2[b * 3], l2v1 = l2[b * 3 + 1], l2v2 = l2[b * 3 + 2];
  const unsigned short* w2b = w2x4 + b * 28672;

  short8 xf[2][2];
  #pragma unroll
  for (int pf = 0; pf < 2; ++pf) {
    int pl = (w << 5) + (pf << 4) + l15;
    float2 ms = *(const float2*)(mr2 + 2 * (size_t)((b << 16) + n0 + pl));
    float muv = ms.x, rsv = ms.y;
    #pragma unroll
    for (int ks = 0; ks < 2; ++ks)
      #pragma unroll
      for (int i = 0; i < 8; ++i) {
        int c = (ks << 5) + (g << 3) + i;
        float v = (io[iob + ((size_t)c << 16) + pl] - muv) * rsv * lw[c] + lb[c];
        xf[pf][ks][i] = (short)f2bs(v);
      }
  }

  f32x4 acc2[2][4] = {{{0,0,0,0},{0,0,0,0},{0,0,0,0},{0,0,0,0}},
                      {{0,0,0,0},{0,0,0,0},{0,0,0,0},{0,0,0,0}}};

  const float GA = -2.3022081f;   // -2*log2(e)*0.7978845608
  const float GB = -0.1029437f;   // -2*log2(e)*0.0356774081

  #pragma unroll 2
  for (int jb = 0; jb < 14; ++jb) {
    int j0 = jb << 5;
    short8 w1a[2][2];
    f32x4 b1v[2];
    #pragma unroll
    for (int q = 0; q < 2; ++q) {
      int ibase = ((jb << 1) | q) << 1;
      w1a[q][0] = *(const short8*)(w1x + ((ibase | 0) << 9) + (l << 3));
      w1a[q][1] = *(const short8*)(w1x + ((ibase | 1) << 9) + (l << 3));
      b1v[q] = *(const f32x4*)(b1f + j0 + (g << 3) + (q << 2));
    }
    short8 A2[2];
    #pragma unroll
    for (int pf = 0; pf < 2; ++pf) {
      #pragma unroll
      for (int q = 0; q < 2; ++q) {
        f32x4 d1 = {0.f, 0.f, 0.f, 0.f};
        d1 = __builtin_amdgcn_mfma_f32_16x16x32_bf16(w1a[q][0], xf[pf][0], d1, 0, 0, 0);
        d1 = __builtin_amdgcn_mfma_f32_16x16x32_bf16(w1a[q][1], xf[pf][1], d1, 0, 0, 0);
        #pragma unroll
        for (int r = 0; r < 4; ++r) {
          float tv = d1[r] + b1v[q][r];
          float t2 = tv * tv;
          float arg = tv * (GA + GB * t2);
          float e1 = __builtin_amdgcn_exp2f(arg);           // raw v_exp_f32
          float gv = tv * __builtin_amdgcn_rcpf(1.f + e1);  // raw v_rcp_f32
          A2[pf][(q << 2) + r] = (short)f2bs(gv);
        }
      }
    }
    #pragma unroll
    for (int ot = 0; ot < 4; ++ot) {
      short8 w2f = *(const short8*)(w2b + (((jb << 2) | ot) << 9) + (l << 3));
      acc2[0][ot] = __builtin_amdgcn_mfma_f32_16x16x32_bf16(A2[0], w2f, acc2[0][ot], 0, 0, 0);
      acc2[1][ot] = __builtin_amdgcn_mfma_f32_16x16x32_bf16(A2[1], w2f, acc2[1][ot], 0, 0, 0);
    }
  }

  #pragma unroll
  for (int ot = 0; ot < 4; ++ot) {
    int o = (ot << 4) + l15;
    float bias = l2v0 * b2_0[o] + l2v1 * b2_1[o] + l2v2 * b2_2[o];
    float gmv = gamma[o];
    #pragma unroll
    for (int pf = 0; pf < 2; ++pf) {
      int p0 = (w << 5) + (pf << 4) + (g << 2);
      float* gp = io + iob + ((size_t)o << 16) + p0;
      f32x4 old = *(const f32x4*)gp;
      f32x4 res;
      #pragma unroll
      for (int r = 0; r < 4; ++r)
        res[r] = acc2[pf][ot][r] + gmv * old[r] + bias;
      *(f32x4*)gp = res;
    }
  }
}

extern "C" void kernel_launch(void* const* d_in, const int* in_sizes, int n_in,
                              void* d_out, int out_size, void* d_ws, size_t ws_size,
                              hipStream_t stream) {
  (void)in_sizes; (void)n_in; (void)out_size; (void)ws_size;
  const float* x        = (const float*)d_in[0];
  const float* hidden   = (const float*)d_in[1];
  const float* ln1_w    = (const float*)d_in[2];
  const float* ln1_b    = (const float*)d_in[3];
  const float* ln2_w    = (const float*)d_in[4];
  const float* ln2_b    = (const float*)d_in[5];
  const float* beta     = (const float*)d_in[6];
  const float* gamma    = (const float*)d_in[7];
  const float* att_temp = (const float*)d_in[8];
  const float* att_qkv  = (const float*)d_in[9];
  const float* att_dw   = (const float*)d_in[10];
  const float* att_proj = (const float*)d_in[11];
  const float* ar1_w    = (const float*)d_in[12];
  const float* ar1_b    = (const float*)d_in[13];
  const float* ar3_w    = (const float*)d_in[14];
  const float* ar3_b    = (const float*)d_in[15];
  const float* mr1_w    = (const float*)d_in[16];
  const float* mr1_b    = (const float*)d_in[17];
  const float* mr3_w    = (const float*)d_in[18];
  const float* mr3_b    = (const float*)d_in[19];
  const float* w1s[3] = {(const float*)d_in[20], (const float*)d_in[24], (const float*)d_in[28]};
  const float* b1s[3] = {(const float*)d_in[21], (const float*)d_in[25], (const float*)d_in[29]};
  const float* w2s[3] = {(const float*)d_in[22], (const float*)d_in[26], (const float*)d_in[30]};
  const float* b2s[3] = {(const float*)d_in[23], (const float*)d_in[27], (const float*)d_in[31]};

  // ---- workspace (~5.6 MB fp32) ----
  float* F    = (float*)d_ws;
  float* mr1b = F + 0;          // 524288 (packed mu,rs per pixel, bank 1)
  float* mr2b = F + 524288;     // 524288 (packed mu,rs per pixel, bank 2)
  float* M    = F + 1048576;    // 16384  (zeroed)
  float* part1= F + 1064960;    // 65536
  float* part2= F + 1130496;    // 65536
  float* smrp = F + 1196032;    // 1024
  float* h1a  = F + 1197056;    // 64
  float* h1m  = F + 1197120;    // 64
  float* l1   = F + 1197184;    // 16
  float* l2   = F + 1197200;    // 16
  float* Weff = F + 1197216;    // 49152
  unsigned short* Ktb = (unsigned short*)(F + 1246368);   // 147456 ushorts
  float* b1f  = F + 1320096;    // 448
  unsigned short* w1x  = (unsigned short*)(F + 1320544);  // 28672 ushorts
  unsigned short* w2x4 = (unsigned short*)(F + 1334880);  // 114688 ushorts

  float* out_main   = (float*)d_out;             // holds out1 between banks
  float* out_hidden = out_main + 16777216;
  float* out_logits = out_main + 16777280;

  // ---- attention bank ----
  k_zero   <<<64, 256, 0, stream>>>(M, 16384);
  k_statsxg<<<1024, 256, 0, stream>>>(x, mr1b, ln1_w, ln1_b, part1, M);
  k_route  <<<1, 256, 0, stream>>>(part1, nullptr, ln1_w, ln1_b, hidden,
                                   ar1_w, ar1_b, ar3_w, ar3_b,
                                   h1a, l1, out_logits, 0, nullptr);
  k_expw   <<<12, 256, 0, stream>>>(M, att_qkv, att_temp, Weff);
  k_kmat   <<<36, 256, 0, stream>>>(Weff, att_dw, att_proj, l1, Ktb);
  k_conv   <<<1024, 256, 0, stream>>>(x, mr1b, ln1_w, ln1_b, Ktb,
                                      beta, out_main, ln2_w, ln2_b,
                                      mr2b, part2, smrp);
  // ---- MLP bank (out1 lives in d_out) ----
  k_route  <<<1, 256, 0, stream>>>(part2, smrp, ln2_w, ln2_b, h1a,
                                   mr1_w, mr1_b, mr3_w, mr3_b,
                                   h1m, l2, out_logits, 1, out_hidden);
  k_prep   <<<112, 256, 0, stream>>>(w1s[0], w1s[1], w1s[2], b1s[0], b1s[1], b1s[2],
                                     w2s[0], w2s[1], w2s[2], l2, w1x, w2x4, b1f);
  k_mlp    <<<2048, 256, 0, stream>>>(out_main, mr2b, ln2_w, ln2_b,
                                      w1x, w2x4, b1f, b2s[0], b2s[1], b2s[2],
                                      gamma, l2);
}